// Round 13
// baseline (196.592 us; speedup 1.0000x reference)
//
#include <hip/hip_runtime.h>
#include <hip/hip_fp16.h>
#include <math.h>

#define H 6
#define D 128
#define K_ALL (H * D)   // 768
#define TSTEPS 24       // K_ALL / 32
#define PADK 776        // 768 + 8 halves pad -> conflict-free fragment reads
#define NPB 8           // nodes per block (1 per wave)

typedef _Float16 f16x8 __attribute__((ext_vector_type(8)));
typedef float f32x4 __attribute__((ext_vector_type(4)));

struct FoldArgs {
    const float* W[4];
    const float* as[4];
    const float* ad[4];
};

// ---------------- CSR build + fused prep ----------------

__global__ __launch_bounds__(256) void zero_kernel(int4* __restrict__ p, int n4) {
    int i = blockIdx.x * 256 + threadIdx.x;
    if (i < n4) p[i] = make_int4(0, 0, 0, 0);
}

// blocks [0, histBlocks): histogram. blocks [histBlocks, +24): wa_all dots.
__global__ __launch_bounds__(256) void hist_prep1_kernel(const int* __restrict__ dst,
                                                         int* __restrict__ deg, int E,
                                                         int histBlocks, FoldArgs fa,
                                                         float* __restrict__ wa_all) {
    int b = blockIdx.x;
    int tid = threadIdx.x;
    if (b < histBlocks) {
        int e = b * 256 + tid;
        if (e < E) atomicAdd(&deg[dst[e]], 1);
    } else {
        int t = (b - histBlocks) * 256 + tid;   // < 6144
        if (t >= 4 * 1536) return;
        int l = t / 1536;
        int r = t % 1536;
        int k = r / 12, j = r % 12;
        int h = (j < 6) ? j : (j - 6);
        const float* att = (j < 6) ? fa.as[l] : fa.ad[l];
        const float* wrow = fa.W[l] + (size_t)k * K_ALL + h * D;
        const float* arow = att + h * D;
        float s = 0.f;
        #pragma unroll 8
        for (int c = 0; c < D; c++) s += wrow[c] * arow[c];
        wa_all[(size_t)l * 1536 + k * 12 + j] = s;
    }
}

// single-pass scan (rowptr) + 128-bin degree histogram/scan (bincur).
__global__ __launch_bounds__(1024) void scan_kernel(const int* __restrict__ deg,
                                                    int* __restrict__ rowptr,
                                                    int* __restrict__ bincur, int n) {
    __shared__ int wsum[16];
    __shared__ int bins[128];
    const int tid = threadIdx.x;
    const int lane = tid & 63;
    const int wv = tid >> 6;
    if (tid < 128) bins[tid] = 0;
    __syncthreads();

    const int base = tid << 4;
    int v[16];
    int tot = 0;
    #pragma unroll
    for (int k = 0; k < 16; k++) {
        int i = base + k;
        int d = (i < n) ? deg[i] : 0;
        v[k] = tot;
        tot += d;
        if (i < n) atomicAdd(&bins[d < 127 ? d : 127], 1);
    }
    int s = tot;
    #pragma unroll
    for (int off = 1; off < 64; off <<= 1) {
        int t = __shfl_up(s, off, 64);
        if (lane >= off) s += t;
    }
    if (lane == 63) wsum[wv] = s;
    __syncthreads();
    if (tid < 16) {
        int t = wsum[tid];
        #pragma unroll
        for (int off = 1; off < 16; off <<= 1) {
            int u = __shfl_up(t, off, 64);
            if ((int)tid >= off) t += u;
        }
        wsum[tid] = t;
    }
    if (tid == 64) {   // serial exclusive scan of 128 bins (separate wave)
        int run = 0;
        for (int b = 0; b < 128; b++) { int c = bins[b]; bins[b] = run; run += c; }
    }
    __syncthreads();
    if (tid < 128) bincur[tid] = bins[tid];
    int off0 = ((wv > 0) ? wsum[wv - 1] : 0) + s - tot;
    #pragma unroll
    for (int k = 0; k < 16; k++) {
        int i = base + k;
        if (i < n) rowptr[i] = off0 + v[k];
    }
}

// blocks: [0,scat): scatter | +3: waf | +192: bf | +perm: degree-bucket perm | +ca: layer-0 a
__global__ __launch_bounds__(256) void scatter_prep2_kernel(const int* __restrict__ src,
                                                            const int* __restrict__ dst,
                                                            int* __restrict__ rowcur,
                                                            int* __restrict__ col, int E,
                                                            int scatBlocks, FoldArgs fa,
                                                            const float* __restrict__ wa_all,
                                                            _Float16* __restrict__ waf,
                                                            _Float16* __restrict__ bf,
                                                            const float* __restrict__ x_in,
                                                            float* __restrict__ a0,
                                                            const int* __restrict__ deg,
                                                            int* __restrict__ bincur,
                                                            int* __restrict__ perm, int N) {
    __shared__ float swa[1536];
    int b = blockIdx.x;
    int tid = threadIdx.x;
    if (b < scatBlocks) {
        int e = b * 256 + tid;
        if (e < E) {
            int p = atomicAdd(&rowcur[dst[e]], 1);
            col[p] = src[e];
        }
        return;
    }
    int bb = b - scatBlocks;
    if (bb < 3) {
        // waf for layer L = bb+1
        int L = bb + 1;
        int lane = tid & 63;
        int t = tid >> 6;
        int j = lane & 15;
        const float* wl = wa_all + (size_t)L * 1536;
        f16x8 v;
        #pragma unroll
        for (int jj = 0; jj < 8; jj++) {
            int k = t * 32 + ((lane >> 4) << 3) + jj;
            float s = (j < 12) ? wl[k * 12 + j] : 0.f;
            v[jj] = (_Float16)s;
        }
        *(f16x8*)(waf + (size_t)bb * 2048 + (size_t)t * 512 + (size_t)lane * 8) = v;
        return;
    }
    bb -= 3;
    if (bb < 192) {
        int idx = bb * 256 + tid;    // < 49152
        int l63 = idx & 63;
        int ct = (idx >> 6) & 7;
        int t = (idx >> 9) % TSTEPS;
        int layer = idx / (TSTEPS * 8 * 64);
        const float* W = fa.W[layer];
        int c = ct * 16 + (l63 & 15);
        f16x8 v;
        #pragma unroll
        for (int j = 0; j < 8; j++) {
            int k = t * 32 + ((l63 >> 4) << 3) + j;
            v[j] = (_Float16)W[(size_t)(k & 127) * K_ALL + ((k >> 7) << 7) + c];
        }
        *(f16x8*)(bf + ((size_t)idx << 3)) = v;
        return;
    }
    bb -= 192;
    int permBlocks = (N + 255) / 256;
    if (bb < permBlocks) {
        int nidx = bb * 256 + tid;
        if (nidx < N) {
            int d = deg[nidx];
            int bin = d < 127 ? d : 127;
            int p = atomicAdd(&bincur[bin], 1);
            perm[p] = nidx;
        }
        return;
    }
    bb -= permBlocks;
    // layer-0 a: one wave per node
    for (int i = tid; i < 1536; i += 256) swa[i] = wa_all[i];
    __syncthreads();
    int lane = tid & 63;
    int wid = bb * 4 + (tid >> 6);
    if (wid >= N) return;
    float x0 = x_in[(size_t)wid * D + lane];
    float x1 = x_in[(size_t)wid * D + 64 + lane];
    #pragma unroll
    for (int j = 0; j < 12; j++) {
        float p = x0 * swa[lane * 12 + j] + x1 * swa[(64 + lane) * 12 + j];
        #pragma unroll
        for (int off = 32; off; off >>= 1) p += __shfl_xor(p, off, 64);
        if (lane == 0) a0[(size_t)wid * 12 + j] = p;
    }
}

__device__ __forceinline__ float rlf(float v, int j) {
    return __int_as_float(__builtin_amdgcn_readlane(__float_as_int(v), j));
}

// per-wave: aggregate node n (softmax over incoming edges + self loop),
// write normalized result as f16 PLAIN layout into LDS row xsrow[0..767].
__device__ __forceinline__ void aggregate_node(const float* __restrict__ x,
                                               const float* __restrict__ a,
                                               const int* __restrict__ rowend,
                                               const int* __restrict__ deg_,
                                               const int* __restrict__ col,
                                               int n, int lane,
                                               _Float16* __restrict__ xsrow) {
    const int deg = deg_[n];
    const int start = rowend[n] - deg;
    const int nent = deg + 1;

    float adst[H];
    #pragma unroll
    for (int h = 0; h < H; h++) adst[h] = a[(size_t)n * 12 + 6 + h];

    if (nent <= 64) {
        const bool act = lane < nent;
        int s = n;                          // lane 'deg' = self loop
        if (lane < deg) s = col[start + lane];

        const float* as_ = a + (size_t)s * 12;
        float4 v0 = *(const float4*)as_;
        float2 v1 = *(const float2*)(as_ + 4);
        float e0 = v0.x + adst[0], e1 = v0.y + adst[1], e2 = v0.z + adst[2];
        float e3 = v0.w + adst[3], e4 = v1.x + adst[4], e5 = v1.y + adst[5];
        e0 = e0 > 0.f ? e0 : 0.2f * e0;  e1 = e1 > 0.f ? e1 : 0.2f * e1;
        e2 = e2 > 0.f ? e2 : 0.2f * e2;  e3 = e3 > 0.f ? e3 : 0.2f * e3;
        e4 = e4 > 0.f ? e4 : 0.2f * e4;  e5 = e5 > 0.f ? e5 : 0.2f * e5;
        if (!act) { e0 = e1 = e2 = e3 = e4 = e5 = -1e30f; }

        float m0 = e0, m1 = e1, m2 = e2, m3 = e3, m4 = e4, m5 = e5;
        #pragma unroll
        for (int off = 32; off; off >>= 1) {
            m0 = fmaxf(m0, __shfl_xor(m0, off, 64));
            m1 = fmaxf(m1, __shfl_xor(m1, off, 64));
            m2 = fmaxf(m2, __shfl_xor(m2, off, 64));
            m3 = fmaxf(m3, __shfl_xor(m3, off, 64));
            m4 = fmaxf(m4, __shfl_xor(m4, off, 64));
            m5 = fmaxf(m5, __shfl_xor(m5, off, 64));
        }
        float w0 = act ? __expf(e0 - m0) : 0.f;
        float w1 = act ? __expf(e1 - m1) : 0.f;
        float w2 = act ? __expf(e2 - m2) : 0.f;
        float w3 = act ? __expf(e3 - m3) : 0.f;
        float w4 = act ? __expf(e4 - m4) : 0.f;
        float w5 = act ? __expf(e5 - m5) : 0.f;
        float d0 = w0, d1 = w1, d2 = w2, d3 = w3, d4 = w4, d5 = w5;
        #pragma unroll
        for (int off = 32; off; off >>= 1) {
            d0 += __shfl_xor(d0, off, 64);  d1 += __shfl_xor(d1, off, 64);
            d2 += __shfl_xor(d2, off, 64);  d3 += __shfl_xor(d3, off, 64);
            d4 += __shfl_xor(d4, off, 64);  d5 += __shfl_xor(d5, off, 64);
        }
        w0 *= 1.f / (d0 + 1e-16f);  w1 *= 1.f / (d1 + 1e-16f);
        w2 *= 1.f / (d2 + 1e-16f);  w3 *= 1.f / (d3 + 1e-16f);
        w4 *= 1.f / (d4 + 1e-16f);  w5 *= 1.f / (d5 + 1e-16f);

        float a00 = 0, a01 = 0, a02 = 0, a03 = 0, a04 = 0, a05 = 0;
        float a10 = 0, a11 = 0, a12 = 0, a13 = 0, a14 = 0, a15 = 0;
        const float* xb = x + (lane << 1);   // channels c=2*lane, 2*lane+1

        float2 xa, xbv;
        {
            int s0 = __builtin_amdgcn_readlane(s, 0);
            xa = *(const float2*)(xb + (size_t)s0 * D);
        }
        xbv = make_float2(0.f, 0.f);
        if (nent > 1) {
            int s1 = __builtin_amdgcn_readlane(s, 1);
            xbv = *(const float2*)(xb + (size_t)s1 * D);
        }
        for (int j = 0; j < nent; j += 2) {
            float2 xn0 = make_float2(0.f, 0.f), xn1 = make_float2(0.f, 0.f);
            if (j + 2 < nent) {
                int s2 = __builtin_amdgcn_readlane(s, j + 2);
                xn0 = *(const float2*)(xb + (size_t)s2 * D);
            }
            if (j + 3 < nent) {
                int s3 = __builtin_amdgcn_readlane(s, j + 3);
                xn1 = *(const float2*)(xb + (size_t)s3 * D);
            }
            {
                float b0 = rlf(w0, j), b1 = rlf(w1, j), b2 = rlf(w2, j);
                float b3 = rlf(w3, j), b4 = rlf(w4, j), b5 = rlf(w5, j);
                a00 += b0 * xa.x; a10 += b0 * xa.y;
                a01 += b1 * xa.x; a11 += b1 * xa.y;
                a02 += b2 * xa.x; a12 += b2 * xa.y;
                a03 += b3 * xa.x; a13 += b3 * xa.y;
                a04 += b4 * xa.x; a14 += b4 * xa.y;
                a05 += b5 * xa.x; a15 += b5 * xa.y;
            }
            if (j + 1 < nent) {
                float b0 = rlf(w0, j + 1), b1 = rlf(w1, j + 1), b2 = rlf(w2, j + 1);
                float b3 = rlf(w3, j + 1), b4 = rlf(w4, j + 1), b5 = rlf(w5, j + 1);
                a00 += b0 * xbv.x; a10 += b0 * xbv.y;
                a01 += b1 * xbv.x; a11 += b1 * xbv.y;
                a02 += b2 * xbv.x; a12 += b2 * xbv.y;
                a03 += b3 * xbv.x; a13 += b3 * xbv.y;
                a04 += b4 * xbv.x; a14 += b4 * xbv.y;
                a05 += b5 * xbv.x; a15 += b5 * xbv.y;
            }
            xa = xn0; xbv = xn1;
        }
        int c = lane << 1;
        xsrow[0 * D + c] = (_Float16)a00;  xsrow[0 * D + c + 1] = (_Float16)a10;
        xsrow[1 * D + c] = (_Float16)a01;  xsrow[1 * D + c + 1] = (_Float16)a11;
        xsrow[2 * D + c] = (_Float16)a02;  xsrow[2 * D + c + 1] = (_Float16)a12;
        xsrow[3 * D + c] = (_Float16)a03;  xsrow[3 * D + c + 1] = (_Float16)a13;
        xsrow[4 * D + c] = (_Float16)a04;  xsrow[4 * D + c + 1] = (_Float16)a14;
        xsrow[5 * D + c] = (_Float16)a05;  xsrow[5 * D + c + 1] = (_Float16)a15;
    } else {
        // slow fallback (deg >= 64): channels c0=lane, c1=64+lane
        float m[H];
        #pragma unroll
        for (int h = 0; h < H; h++) {
            float e = a[(size_t)n * 12 + h] + adst[h];
            m[h] = (e > 0.f) ? e : 0.2f * e;
        }
        for (int j = 0; j < deg; j++) {
            int s = col[start + j];
            #pragma unroll
            for (int h = 0; h < H; h++) {
                float e = a[(size_t)s * 12 + h] + adst[h];
                e = (e > 0.f) ? e : 0.2f * e;
                m[h] = fmaxf(m[h], e);
            }
        }
        float d[H] = {0, 0, 0, 0, 0, 0};
        float acc0[H] = {0, 0, 0, 0, 0, 0};
        float acc1[H] = {0, 0, 0, 0, 0, 0};
        int c0 = lane, c1 = 64 + lane;
        for (int j = 0; j <= deg; j++) {
            int s = (j < deg) ? col[start + j] : n;
            float w[H];
            #pragma unroll
            for (int h = 0; h < H; h++) {
                float e = a[(size_t)s * 12 + h] + adst[h];
                e = (e > 0.f) ? e : 0.2f * e;
                w[h] = __expf(e - m[h]);
                d[h] += w[h];
            }
            float xv0 = x[(size_t)s * D + c0];
            float xv1 = x[(size_t)s * D + c1];
            #pragma unroll
            for (int h = 0; h < H; h++) {
                acc0[h] += w[h] * xv0;
                acc1[h] += w[h] * xv1;
            }
        }
        #pragma unroll
        for (int h = 0; h < H; h++) {
            float inv = 1.0f / (d[h] + 1e-16f);
            xsrow[h * D + c0] = (_Float16)(acc0[h] * inv);
            xsrow[h * D + c1] = (_Float16)(acc1[h] * inv);
        }
    }
}

// ---------------- fused layer: aggregate(8 perm'd nodes -> LDS) + MFMA GEMM + a ----------------
// Degree-sorted perm: each block's 8 waves get near-equal-degree nodes ->
// minimal __syncthreads tail. Rows 8..15 of A are garbage (pollute only
// D rows 8..15, never stored).
__global__ __launch_bounds__(512) void layer_kernel(const float* __restrict__ x,
                                                    const float* __restrict__ a_in,
                                                    const int* __restrict__ rowend,
                                                    const int* __restrict__ deg_,
                                                    const int* __restrict__ col,
                                                    const int* __restrict__ perm,
                                                    const _Float16* __restrict__ bf,
                                                    const float* __restrict__ bias,
                                                    float* __restrict__ xout,
                                                    const _Float16* __restrict__ awf,
                                                    float* __restrict__ a_out, int M) {
    __shared__ _Float16 xs16[16][PADK];   // rows 0..7 aggregated; 8..15 garbage
    __shared__ _Float16 xso[16][136];     // output rows (f16) for fused a
    const int wave = (int)(threadIdx.x >> 6);
    const int lane = (int)(threadIdx.x & 63);
    const int m0 = (int)(blockIdx.x << 3);

    // phase 1: each wave aggregates 1 node (perm'd)
    {
        int mi = m0 + wave;
        if (mi < M) {
            int n = perm[mi];
            aggregate_node(x, a_in, rowend, deg_, col, n, lane, &xs16[wave][0]);
        }
    }
    __syncthreads();

    // phase 2: GEMM — wave w owns col-tile w (cols w*16..w*16+15)
    f32x4 acc = {0.f, 0.f, 0.f, 0.f};
    const _Float16* ars = &xs16[lane & 15][(lane >> 4) << 3];
    const _Float16* bp = bf + (size_t)wave * 512 + (size_t)lane * 8;
    for (int t = 0; t < TSTEPS; t++) {
        f16x8 av = *(const f16x8*)(ars + t * 32);
        f16x8 bv = *(const f16x8*)(bp + (size_t)t * 4096);
        acc = __builtin_amdgcn_mfma_f32_16x16x32_f16(av, bv, acc, 0, 0, 0);
    }

    const float inv6 = 1.0f / 6.0f;
    const int cl = lane & 15;
    const int ccol = wave * 16 + cl;
    const int r0 = (lane >> 4) << 2;
    const float bs = bias[ccol];
    #pragma unroll
    for (int reg = 0; reg < 4; reg++) {
        int ml = r0 + reg;
        int mi = m0 + ml;
        float v = acc[reg] * inv6 + bs;
        v = v > 0.f ? v : 0.f;
        if (ml < NPB && mi < M) xout[(size_t)perm[mi] * D + ccol] = v;
        xso[ml][ccol] = (_Float16)v;
    }

    // phase 3: fused next-layer attention logits (wave 0)
    if (awf) {
        __syncthreads();
        if (wave == 0) {
            f32x4 ac = {0.f, 0.f, 0.f, 0.f};
            #pragma unroll
            for (int t = 0; t < 4; t++) {
                f16x8 av = *(const f16x8*)&xso[cl][t * 32 + ((lane >> 4) << 3)];
                f16x8 bv = *(const f16x8*)(awf + (size_t)t * 512 + (size_t)lane * 8);
                ac = __builtin_amdgcn_mfma_f32_16x16x32_f16(av, bv, ac, 0, 0, 0);
            }
            if (cl < 12) {
                #pragma unroll
                for (int reg = 0; reg < 4; reg++) {
                    int ml = r0 + reg;
                    int mi = m0 + ml;
                    if (ml < NPB && mi < M) a_out[(size_t)perm[mi] * 12 + cl] = ac[reg];
                }
            }
        }
    }
}

// ---------------- host ----------------

extern "C" void kernel_launch(void* const* d_in, const int* in_sizes, int n_in,
                              void* d_out, int out_size, void* d_ws, size_t ws_size,
                              hipStream_t stream) {
    const float* x_in = (const float*)d_in[0];
    const int* ei = (const int*)d_in[1];
    int N = in_sizes[0] / D;
    int E = in_sizes[1] / 2;
    const int* srcp = ei;
    const int* dstp = ei + E;

    size_t bf_halves_per_layer = (size_t)TSTEPS * 8 * 512;   // 98304

    float* ws = (float*)d_ws;
    float* bufA = ws;
    float* bufB = bufA + (size_t)N * D;
    float* abuf0 = bufB + (size_t)N * D;
    float* abuf1 = abuf0 + (size_t)N * 12;
    float* wa_all = abuf1 + (size_t)N * 12;          // 4*1536 floats
    _Float16* waf = (_Float16*)(wa_all + 4 * 1536);  // 3 layers x 2048 halves
    _Float16* w16f = waf + 3 * 2048;
    int* deg = (int*)(w16f + 4 * bf_halves_per_layer);
    int* bincur = deg + N;          // 128
    int* rowptr = bincur + 128;     // N+1
    int* col = rowptr + (N + 1);    // E
    int* perm = col + E;            // N

    FoldArgs fa;
    for (int l = 0; l < 4; l++) {
        fa.W[l]  = (const float*)d_in[2 + 4 * l];
        fa.as[l] = (const float*)d_in[3 + 4 * l];
        fa.ad[l] = (const float*)d_in[4 + 4 * l];
    }

    // CSR build + fused prep (zero covers deg + bincur)
    int n4 = (N + 128 + 3) / 4;
    zero_kernel<<<(n4 + 255) / 256, 256, 0, stream>>>((int4*)deg, n4);
    int histBlocks = (E + 255) / 256;
    hist_prep1_kernel<<<histBlocks + 24, 256, 0, stream>>>(dstp, deg, E, histBlocks, fa, wa_all);
    scan_kernel<<<1, 1024, 0, stream>>>(deg, rowptr, bincur, N);
    int scatBlocks = (E + 255) / 256;
    int permBlocks = (N + 255) / 256;
    int caBlocks = (N + 3) / 4;
    scatter_prep2_kernel<<<scatBlocks + 3 + 192 + permBlocks + caBlocks, 256, 0, stream>>>(
        srcp, dstp, rowptr, col, E, scatBlocks, fa, wa_all, waf, w16f, x_in, abuf0,
        deg, bincur, perm, N);

    const float* xcur = x_in;
    float* acur = abuf0;
    float* anext = abuf1;
    for (int l = 0; l < 4; l++) {
        const float* b = (const float*)d_in[5 + 4 * l];
        float* xout = (l == 3) ? (float*)d_out : ((l & 1) ? bufB : bufA);
        const _Float16* awf = (l < 3) ? (waf + (size_t)l * 2048) : (const _Float16*)nullptr;

        layer_kernel<<<(N + NPB - 1) / NPB, 512, 0, stream>>>(xcur, acur, rowptr, deg, col, perm,
                                                              w16f + (size_t)l * bf_halves_per_layer,
                                                              b, xout, awf, anext, N);
        xcur = xout;
        float* tmp = acur; acur = anext; anext = tmp;
    }
}

// Round 14
// 172.885 us; speedup vs baseline: 1.1371x; 1.1371x over previous
//
#include <hip/hip_runtime.h>
#include <hip/hip_fp16.h>
#include <math.h>

#define H 6
#define D 128
#define K_ALL (H * D)   // 768
#define TSTEPS 24       // K_ALL / 32
#define PADK 776        // 768 + 8 halves pad -> conflict-free fragment reads
#define NPB 8           // nodes per block (1 per wave)

typedef _Float16 f16x8 __attribute__((ext_vector_type(8)));
typedef float f32x4 __attribute__((ext_vector_type(4)));

struct FoldArgs {
    const float* W[4];
    const float* as[4];
    const float* ad[4];
};

// ---------------- CSR build + fused prep ----------------

__global__ __launch_bounds__(256) void zero_kernel(int4* __restrict__ p, int n4) {
    int i = blockIdx.x * 256 + threadIdx.x;
    if (i < n4) p[i] = make_int4(0, 0, 0, 0);
}

// blocks [0, histBlocks): histogram. blocks [histBlocks, +24): wa_all dots.
__global__ __launch_bounds__(256) void hist_prep1_kernel(const int* __restrict__ dst,
                                                         int* __restrict__ deg, int E,
                                                         int histBlocks, FoldArgs fa,
                                                         float* __restrict__ wa_all) {
    int b = blockIdx.x;
    int tid = threadIdx.x;
    if (b < histBlocks) {
        int e = b * 256 + tid;
        if (e < E) atomicAdd(&deg[dst[e]], 1);
    } else {
        int t = (b - histBlocks) * 256 + tid;   // < 6144
        if (t >= 4 * 1536) return;
        int l = t / 1536;
        int r = t % 1536;
        int k = r / 12, j = r % 12;
        int h = (j < 6) ? j : (j - 6);
        const float* att = (j < 6) ? fa.as[l] : fa.ad[l];
        const float* wrow = fa.W[l] + (size_t)k * K_ALL + h * D;
        const float* arow = att + h * D;
        float s = 0.f;
        #pragma unroll 8
        for (int c = 0; c < D; c++) s += wrow[c] * arow[c];
        wa_all[(size_t)l * 1536 + k * 12 + j] = s;
    }
}

// single-pass scan: thread i owns elements [i*16, i*16+16); 2 barriers total.
__global__ __launch_bounds__(1024) void scan_kernel(const int* __restrict__ deg,
                                                    int* __restrict__ rowptr, int n) {
    __shared__ int wsum[16];
    const int tid = threadIdx.x;
    const int lane = tid & 63;
    const int wv = tid >> 6;
    const int base = tid << 4;

    int v[16];
    int tot = 0;
    #pragma unroll
    for (int k = 0; k < 16; k++) {
        int i = base + k;
        int d = (i < n) ? deg[i] : 0;
        v[k] = tot;
        tot += d;
    }
    int s = tot;
    #pragma unroll
    for (int off = 1; off < 64; off <<= 1) {
        int t = __shfl_up(s, off, 64);
        if (lane >= off) s += t;
    }
    if (lane == 63) wsum[wv] = s;
    __syncthreads();
    if (tid < 16) {
        int t = wsum[tid];
        #pragma unroll
        for (int off = 1; off < 16; off <<= 1) {
            int u = __shfl_up(t, off, 64);
            if ((int)tid >= off) t += u;
        }
        wsum[tid] = t;
    }
    __syncthreads();
    int off0 = ((wv > 0) ? wsum[wv - 1] : 0) + s - tot;
    #pragma unroll
    for (int k = 0; k < 16; k++) {
        int i = base + k;
        if (i < n) rowptr[i] = off0 + v[k];
    }
}

// blocks: [0,scat): scatter | +3: waf pack | +192: bf pack | +caBlocks: layer-0 a
__global__ __launch_bounds__(256) void scatter_prep2_kernel(const int* __restrict__ src,
                                                            const int* __restrict__ dst,
                                                            int* __restrict__ rowcur,
                                                            int* __restrict__ col, int E,
                                                            int scatBlocks, FoldArgs fa,
                                                            const float* __restrict__ wa_all,
                                                            _Float16* __restrict__ waf,
                                                            _Float16* __restrict__ bf,
                                                            const float* __restrict__ x_in,
                                                            float* __restrict__ a0, int N) {
    __shared__ float swa[1536];
    int b = blockIdx.x;
    int tid = threadIdx.x;
    if (b < scatBlocks) {
        int e = b * 256 + tid;
        if (e < E) {
            int p = atomicAdd(&rowcur[dst[e]], 1);
            col[p] = src[e];
        }
        return;
    }
    int bb = b - scatBlocks;
    if (bb < 3) {
        // waf for layer L = bb+1
        int L = bb + 1;
        int lane = tid & 63;
        int t = tid >> 6;
        int j = lane & 15;
        const float* wl = wa_all + (size_t)L * 1536;
        f16x8 v;
        #pragma unroll
        for (int jj = 0; jj < 8; jj++) {
            int k = t * 32 + ((lane >> 4) << 3) + jj;
            float s = (j < 12) ? wl[k * 12 + j] : 0.f;
            v[jj] = (_Float16)s;
        }
        *(f16x8*)(waf + (size_t)bb * 2048 + (size_t)t * 512 + (size_t)lane * 8) = v;
        return;
    }
    bb -= 3;
    if (bb < 192) {
        int idx = bb * 256 + tid;    // < 49152
        int l63 = idx & 63;
        int ct = (idx >> 6) & 7;
        int t = (idx >> 9) % TSTEPS;
        int layer = idx / (TSTEPS * 8 * 64);
        const float* W = fa.W[layer];
        int c = ct * 16 + (l63 & 15);
        f16x8 v;
        #pragma unroll
        for (int j = 0; j < 8; j++) {
            int k = t * 32 + ((l63 >> 4) << 3) + j;
            v[j] = (_Float16)W[(size_t)(k & 127) * K_ALL + ((k >> 7) << 7) + c];
        }
        *(f16x8*)(bf + ((size_t)idx << 3)) = v;
        return;
    }
    bb -= 192;
    // layer-0 a: one wave per node
    for (int i = tid; i < 1536; i += 256) swa[i] = wa_all[i];
    __syncthreads();
    int lane = tid & 63;
    int wid = bb * 4 + (tid >> 6);
    if (wid >= N) return;
    float x0 = x_in[(size_t)wid * D + lane];
    float x1 = x_in[(size_t)wid * D + 64 + lane];
    #pragma unroll
    for (int j = 0; j < 12; j++) {
        float p = x0 * swa[lane * 12 + j] + x1 * swa[(64 + lane) * 12 + j];
        #pragma unroll
        for (int off = 32; off; off >>= 1) p += __shfl_xor(p, off, 64);
        if (lane == 0) a0[(size_t)wid * 12 + j] = p;
    }
}

__device__ __forceinline__ float rlf(float v, int j) {
    return __int_as_float(__builtin_amdgcn_readlane(__float_as_int(v), j));
}

// per-wave: aggregate node n. NO cross-lane reductions: softmax computed
// WITHOUT max-subtract (logits are O(10), exp safe in f32; softmax is
// shift-invariant) and the denominator is accumulated from the readlane
// broadcasts every lane already receives (d += b, identical in all lanes).
// This removes all 72 DS-pipe shuffles / 2 serial 6-deep chains per node
// that r10/r12 nulls identified as the latency bound.
__device__ __forceinline__ void aggregate_node(const float* __restrict__ x,
                                               const float* __restrict__ a,
                                               const int* __restrict__ rowend,
                                               const int* __restrict__ deg_,
                                               const int* __restrict__ col,
                                               int n, int lane,
                                               _Float16* __restrict__ xsrow) {
    const int deg = deg_[n];
    const int start = rowend[n] - deg;
    const int nent = deg + 1;

    float adst[H];
    #pragma unroll
    for (int h = 0; h < H; h++) adst[h] = a[(size_t)n * 12 + 6 + h];

    if (nent <= 64) {
        int s = n;                          // lane 'deg' = self loop
        if (lane < deg) s = col[start + lane];

        const float* as_ = a + (size_t)s * 12;
        float4 v0 = *(const float4*)as_;
        float2 v1 = *(const float2*)(as_ + 4);
        float e0 = v0.x + adst[0], e1 = v0.y + adst[1], e2 = v0.z + adst[2];
        float e3 = v0.w + adst[3], e4 = v1.x + adst[4], e5 = v1.y + adst[5];
        e0 = e0 > 0.f ? e0 : 0.2f * e0;  e1 = e1 > 0.f ? e1 : 0.2f * e1;
        e2 = e2 > 0.f ? e2 : 0.2f * e2;  e3 = e3 > 0.f ? e3 : 0.2f * e3;
        e4 = e4 > 0.f ? e4 : 0.2f * e4;  e5 = e5 > 0.f ? e5 : 0.2f * e5;
        // unnormalized weights (lanes >= nent never broadcast; no masking needed)
        float w0 = __expf(e0), w1 = __expf(e1), w2 = __expf(e2);
        float w3 = __expf(e3), w4 = __expf(e4), w5 = __expf(e5);

        float d0 = 0, d1 = 0, d2 = 0, d3 = 0, d4 = 0, d5 = 0;
        float a00 = 0, a01 = 0, a02 = 0, a03 = 0, a04 = 0, a05 = 0;
        float a10 = 0, a11 = 0, a12 = 0, a13 = 0, a14 = 0, a15 = 0;
        const float* xb = x + (lane << 1);   // channels c=2*lane, 2*lane+1

        float2 xa, xbv;
        {
            int s0 = __builtin_amdgcn_readlane(s, 0);
            xa = *(const float2*)(xb + (size_t)s0 * D);
        }
        xbv = make_float2(0.f, 0.f);
        if (nent > 1) {
            int s1 = __builtin_amdgcn_readlane(s, 1);
            xbv = *(const float2*)(xb + (size_t)s1 * D);
        }
        for (int j = 0; j < nent; j += 2) {
            float2 xn0 = make_float2(0.f, 0.f), xn1 = make_float2(0.f, 0.f);
            if (j + 2 < nent) {
                int s2 = __builtin_amdgcn_readlane(s, j + 2);
                xn0 = *(const float2*)(xb + (size_t)s2 * D);
            }
            if (j + 3 < nent) {
                int s3 = __builtin_amdgcn_readlane(s, j + 3);
                xn1 = *(const float2*)(xb + (size_t)s3 * D);
            }
            {
                float b0 = rlf(w0, j), b1 = rlf(w1, j), b2 = rlf(w2, j);
                float b3 = rlf(w3, j), b4 = rlf(w4, j), b5 = rlf(w5, j);
                d0 += b0; d1 += b1; d2 += b2; d3 += b3; d4 += b4; d5 += b5;
                a00 += b0 * xa.x; a10 += b0 * xa.y;
                a01 += b1 * xa.x; a11 += b1 * xa.y;
                a02 += b2 * xa.x; a12 += b2 * xa.y;
                a03 += b3 * xa.x; a13 += b3 * xa.y;
                a04 += b4 * xa.x; a14 += b4 * xa.y;
                a05 += b5 * xa.x; a15 += b5 * xa.y;
            }
            if (j + 1 < nent) {
                float b0 = rlf(w0, j + 1), b1 = rlf(w1, j + 1), b2 = rlf(w2, j + 1);
                float b3 = rlf(w3, j + 1), b4 = rlf(w4, j + 1), b5 = rlf(w5, j + 1);
                d0 += b0; d1 += b1; d2 += b2; d3 += b3; d4 += b4; d5 += b5;
                a00 += b0 * xbv.x; a10 += b0 * xbv.y;
                a01 += b1 * xbv.x; a11 += b1 * xbv.y;
                a02 += b2 * xbv.x; a12 += b2 * xbv.y;
                a03 += b3 * xbv.x; a13 += b3 * xbv.y;
                a04 += b4 * xbv.x; a14 += b4 * xbv.y;
                a05 += b5 * xbv.x; a15 += b5 * xbv.y;
            }
            xa = xn0; xbv = xn1;
        }
        float i0 = 1.f / d0, i1 = 1.f / d1, i2 = 1.f / d2;
        float i3 = 1.f / d3, i4 = 1.f / d4, i5 = 1.f / d5;
        int c = lane << 1;
        xsrow[0 * D + c] = (_Float16)(a00 * i0);  xsrow[0 * D + c + 1] = (_Float16)(a10 * i0);
        xsrow[1 * D + c] = (_Float16)(a01 * i1);  xsrow[1 * D + c + 1] = (_Float16)(a11 * i1);
        xsrow[2 * D + c] = (_Float16)(a02 * i2);  xsrow[2 * D + c + 1] = (_Float16)(a12 * i2);
        xsrow[3 * D + c] = (_Float16)(a03 * i3);  xsrow[3 * D + c + 1] = (_Float16)(a13 * i3);
        xsrow[4 * D + c] = (_Float16)(a04 * i4);  xsrow[4 * D + c + 1] = (_Float16)(a14 * i4);
        xsrow[5 * D + c] = (_Float16)(a05 * i5);  xsrow[5 * D + c + 1] = (_Float16)(a15 * i5);
    } else {
        // slow fallback (deg >= 64): single pass, no max-subtract
        float d[H] = {0, 0, 0, 0, 0, 0};
        float acc0[H] = {0, 0, 0, 0, 0, 0};
        float acc1[H] = {0, 0, 0, 0, 0, 0};
        int c0 = lane, c1 = 64 + lane;
        for (int j = 0; j <= deg; j++) {
            int s = (j < deg) ? col[start + j] : n;
            float w[H];
            #pragma unroll
            for (int h = 0; h < H; h++) {
                float e = a[(size_t)s * 12 + h] + adst[h];
                e = (e > 0.f) ? e : 0.2f * e;
                w[h] = __expf(e);
                d[h] += w[h];
            }
            float xv0 = x[(size_t)s * D + c0];
            float xv1 = x[(size_t)s * D + c1];
            #pragma unroll
            for (int h = 0; h < H; h++) {
                acc0[h] += w[h] * xv0;
                acc1[h] += w[h] * xv1;
            }
        }
        #pragma unroll
        for (int h = 0; h < H; h++) {
            float inv = 1.0f / d[h];
            xsrow[h * D + c0] = (_Float16)(acc0[h] * inv);
            xsrow[h * D + c1] = (_Float16)(acc1[h] * inv);
        }
    }
}

// ---------------- fused layer: aggregate(8 nodes -> LDS) + MFMA GEMM + a ----------------
__global__ __launch_bounds__(512) void layer_kernel(const float* __restrict__ x,
                                                    const float* __restrict__ a_in,
                                                    const int* __restrict__ rowend,
                                                    const int* __restrict__ deg_,
                                                    const int* __restrict__ col,
                                                    const _Float16* __restrict__ bf,
                                                    const float* __restrict__ bias,
                                                    float* __restrict__ xout,
                                                    const _Float16* __restrict__ awf,
                                                    float* __restrict__ a_out, int M) {
    __shared__ _Float16 xs16[16][PADK];   // rows 0..7 aggregated; 8..15 garbage
    __shared__ _Float16 xso[16][136];     // output rows (f16) for fused a
    const int wave = (int)(threadIdx.x >> 6);
    const int lane = (int)(threadIdx.x & 63);
    const int m0 = (int)(blockIdx.x << 3);

    // phase 1: each wave aggregates 1 node
    {
        int n = m0 + wave;
        if (n < M)
            aggregate_node(x, a_in, rowend, deg_, col, n, lane, &xs16[wave][0]);
    }
    __syncthreads();

    // phase 2: GEMM — wave w owns col-tile w (cols w*16..w*16+15)
    f32x4 acc = {0.f, 0.f, 0.f, 0.f};
    const _Float16* ars = &xs16[lane & 15][(lane >> 4) << 3];
    const _Float16* bp = bf + (size_t)wave * 512 + (size_t)lane * 8;
    for (int t = 0; t < TSTEPS; t++) {
        f16x8 av = *(const f16x8*)(ars + t * 32);
        f16x8 bv = *(const f16x8*)(bp + (size_t)t * 4096);
        acc = __builtin_amdgcn_mfma_f32_16x16x32_f16(av, bv, acc, 0, 0, 0);
    }

    const float inv6 = 1.0f / 6.0f;
    const int cl = lane & 15;
    const int ccol = wave * 16 + cl;
    const int r0 = (lane >> 4) << 2;
    const float bs = bias[ccol];
    #pragma unroll
    for (int reg = 0; reg < 4; reg++) {
        int ml = r0 + reg;
        int m = m0 + ml;
        float v = acc[reg] * inv6 + bs;
        v = v > 0.f ? v : 0.f;
        if (ml < NPB && m < M) xout[(size_t)m * D + ccol] = v;
        xso[ml][ccol] = (_Float16)v;
    }

    // phase 3: fused next-layer attention logits (wave 0)
    if (awf) {
        __syncthreads();
        if (wave == 0) {
            f32x4 ac = {0.f, 0.f, 0.f, 0.f};
            #pragma unroll
            for (int t = 0; t < 4; t++) {
                f16x8 av = *(const f16x8*)&xso[cl][t * 32 + ((lane >> 4) << 3)];
                f16x8 bv = *(const f16x8*)(awf + (size_t)t * 512 + (size_t)lane * 8);
                ac = __builtin_amdgcn_mfma_f32_16x16x32_f16(av, bv, ac, 0, 0, 0);
            }
            if (cl < 12) {
                #pragma unroll
                for (int reg = 0; reg < 4; reg++) {
                    int ml = r0 + reg;
                    int m = m0 + ml;
                    if (ml < NPB && m < M) a_out[(size_t)m * 12 + cl] = ac[reg];
                }
            }
        }
    }
}

// ---------------- host ----------------

extern "C" void kernel_launch(void* const* d_in, const int* in_sizes, int n_in,
                              void* d_out, int out_size, void* d_ws, size_t ws_size,
                              hipStream_t stream) {
    const float* x_in = (const float*)d_in[0];
    const int* ei = (const int*)d_in[1];
    int N = in_sizes[0] / D;
    int E = in_sizes[1] / 2;
    const int* srcp = ei;
    const int* dstp = ei + E;

    size_t bf_halves_per_layer = (size_t)TSTEPS * 8 * 512;   // 98304

    float* ws = (float*)d_ws;
    float* bufA = ws;
    float* bufB = bufA + (size_t)N * D;
    float* abuf0 = bufB + (size_t)N * D;
    float* abuf1 = abuf0 + (size_t)N * 12;
    float* wa_all = abuf1 + (size_t)N * 12;          // 4*1536 floats
    _Float16* waf = (_Float16*)(wa_all + 4 * 1536);  // 3 layers x 2048 halves
    _Float16* w16f = waf + 3 * 2048;
    int* deg = (int*)(w16f + 4 * bf_halves_per_layer);
    int* rowptr = deg + N;
    int* col = rowptr + (N + 1);

    FoldArgs fa;
    for (int l = 0; l < 4; l++) {
        fa.W[l]  = (const float*)d_in[2 + 4 * l];
        fa.as[l] = (const float*)d_in[3 + 4 * l];
        fa.ad[l] = (const float*)d_in[4 + 4 * l];
    }

    // CSR build + fused prep
    int n4 = (N + 3) / 4;
    zero_kernel<<<(n4 + 255) / 256, 256, 0, stream>>>((int4*)deg, n4);
    int histBlocks = (E + 255) / 256;
    hist_prep1_kernel<<<histBlocks + 24, 256, 0, stream>>>(dstp, deg, E, histBlocks, fa, wa_all);
    scan_kernel<<<1, 1024, 0, stream>>>(deg, rowptr, N);
    int scatBlocks = (E + 255) / 256;
    int caBlocks = (N + 3) / 4;
    scatter_prep2_kernel<<<scatBlocks + 3 + 192 + caBlocks, 256, 0, stream>>>(
        srcp, dstp, rowptr, col, E, scatBlocks, fa, wa_all, waf, w16f, x_in, abuf0, N);

    const float* xcur = x_in;
    float* acur = abuf0;
    float* anext = abuf1;
    for (int l = 0; l < 4; l++) {
        const float* b = (const float*)d_in[5 + 4 * l];
        float* xout = (l == 3) ? (float*)d_out : ((l & 1) ? bufB : bufA);
        const _Float16* awf = (l < 3) ? (waf + (size_t)l * 2048) : (const _Float16*)nullptr;

        layer_kernel<<<(N + NPB - 1) / NPB, 512, 0, stream>>>(xcur, acur, rowptr, deg, col,
                                                              w16f + (size_t)l * bf_halves_per_layer,
                                                              b, xout, awf, anext, N);
        xcur = xout;
        float* tmp = acur; acur = anext; anext = tmp;
    }
}

// Round 15
// 163.007 us; speedup vs baseline: 1.2060x; 1.0606x over previous
//
#include <hip/hip_runtime.h>
#include <hip/hip_fp16.h>
#include <math.h>

#define H 6
#define D 128
#define K_ALL (H * D)   // 768
#define TSTEPS 24       // K_ALL / 32
#define PADK 776        // 768 + 8 halves pad -> conflict-free fragment reads
#define NPB 8           // nodes per block (1 per wave)

typedef _Float16 f16x8 __attribute__((ext_vector_type(8)));
typedef float f32x4 __attribute__((ext_vector_type(4)));

struct FoldArgs {
    const float* W[4];
    const float* as[4];
    const float* ad[4];
};

// ---------------- CSR build + fused prep ----------------

__global__ __launch_bounds__(256) void zero_kernel(int4* __restrict__ p, int n4) {
    int i = blockIdx.x * 256 + threadIdx.x;
    if (i < n4) p[i] = make_int4(0, 0, 0, 0);
}

// blocks [0, histBlocks): histogram. blocks [histBlocks, +24): wa_all dots.
__global__ __launch_bounds__(256) void hist_prep1_kernel(const int* __restrict__ dst,
                                                         int* __restrict__ deg, int E,
                                                         int histBlocks, FoldArgs fa,
                                                         float* __restrict__ wa_all) {
    int b = blockIdx.x;
    int tid = threadIdx.x;
    if (b < histBlocks) {
        int e = b * 256 + tid;
        if (e < E) atomicAdd(&deg[dst[e]], 1);
    } else {
        int t = (b - histBlocks) * 256 + tid;   // < 6144
        if (t >= 4 * 1536) return;
        int l = t / 1536;
        int r = t % 1536;
        int k = r / 12, j = r % 12;
        int h = (j < 6) ? j : (j - 6);
        const float* att = (j < 6) ? fa.as[l] : fa.ad[l];
        const float* wrow = fa.W[l] + (size_t)k * K_ALL + h * D;
        const float* arow = att + h * D;
        float s = 0.f;
        #pragma unroll 8
        for (int c = 0; c < D; c++) s += wrow[c] * arow[c];
        wa_all[(size_t)l * 1536 + k * 12 + j] = s;
    }
}

// single-pass scan (rowptr) + waf fragment pack for ALL 4 layers
// (1024 threads == 4 layers x 4 t-steps x 64 lanes, one f16x8 each).
__global__ __launch_bounds__(1024) void scan_kernel(const int* __restrict__ deg,
                                                    int* __restrict__ rowptr, int n,
                                                    const float* __restrict__ wa_all,
                                                    _Float16* __restrict__ waf) {
    __shared__ int wsum[16];
    const int tid = threadIdx.x;
    const int lane = tid & 63;
    const int wv = tid >> 6;
    const int base = tid << 4;

    int v[16];
    int tot = 0;
    #pragma unroll
    for (int k = 0; k < 16; k++) {
        int i = base + k;
        int d = (i < n) ? deg[i] : 0;
        v[k] = tot;
        tot += d;
    }
    int s = tot;
    #pragma unroll
    for (int off = 1; off < 64; off <<= 1) {
        int t = __shfl_up(s, off, 64);
        if (lane >= off) s += t;
    }
    if (lane == 63) wsum[wv] = s;
    __syncthreads();
    if (tid < 16) {
        int t = wsum[tid];
        #pragma unroll
        for (int off = 1; off < 16; off <<= 1) {
            int u = __shfl_up(t, off, 64);
            if ((int)tid >= off) t += u;
        }
        wsum[tid] = t;
    }
    __syncthreads();
    int off0 = ((wv > 0) ? wsum[wv - 1] : 0) + s - tot;
    #pragma unroll
    for (int k = 0; k < 16; k++) {
        int i = base + k;
        if (i < n) rowptr[i] = off0 + v[k];
    }

    // waf pack: L = tid>>8, t = (tid>>6)&3, frag lane = tid&63
    {
        int L = tid >> 8;
        int t = (tid >> 6) & 3;
        int j = lane & 15;
        const float* wl = wa_all + (size_t)L * 1536;
        f16x8 vv;
        #pragma unroll
        for (int jj = 0; jj < 8; jj++) {
            int k = t * 32 + ((lane >> 4) << 3) + jj;
            float sv = (j < 12) ? wl[k * 12 + j] : 0.f;
            vv[jj] = (_Float16)sv;
        }
        *(f16x8*)(waf + (size_t)L * 2048 + (size_t)t * 512 + (size_t)lane * 8) = vv;
    }
}

// blocks: [0,scat): scatter | +192: bf pack | +a0Blocks: layer-0 a via MFMA
__global__ __launch_bounds__(256) void scatter_prep2_kernel(const int* __restrict__ src,
                                                            const int* __restrict__ dst,
                                                            int* __restrict__ rowcur,
                                                            int* __restrict__ col, int E,
                                                            int scatBlocks, FoldArgs fa,
                                                            const _Float16* __restrict__ waf,
                                                            _Float16* __restrict__ bf,
                                                            const float* __restrict__ x_in,
                                                            float* __restrict__ a0, int N) {
    __shared__ _Float16 xs[16][136];
    int b = blockIdx.x;
    int tid = threadIdx.x;
    if (b < scatBlocks) {
        int e = b * 256 + tid;
        if (e < E) {
            int p = atomicAdd(&rowcur[dst[e]], 1);
            col[p] = src[e];
        }
        return;
    }
    int bb = b - scatBlocks;
    if (bb < 192) {
        int idx = bb * 256 + tid;    // < 49152
        int l63 = idx & 63;
        int ct = (idx >> 6) & 7;
        int t = (idx >> 9) % TSTEPS;
        int layer = idx / (TSTEPS * 8 * 64);
        const float* W = fa.W[layer];
        int c = ct * 16 + (l63 & 15);
        f16x8 v;
        #pragma unroll
        for (int j = 0; j < 8; j++) {
            int k = t * 32 + ((l63 >> 4) << 3) + j;
            v[j] = (_Float16)W[(size_t)(k & 127) * K_ALL + ((k >> 7) << 7) + c];
        }
        *(f16x8*)(bf + ((size_t)idx << 3)) = v;
        return;
    }
    bb -= 192;
    // layer-0 a via MFMA: 16 nodes per block
    int base_node = bb << 4;
    {
        int row = tid >> 4;                 // 0..15
        int coff = (tid & 15) * 8;          // 0..120
        int node = base_node + row;
        f16x8 v = {};
        if (node < N) {
            const float* sp = x_in + (size_t)node * D + coff;
            float4 u0 = *(const float4*)sp;
            float4 u1 = *(const float4*)(sp + 4);
            v[0] = (_Float16)u0.x; v[1] = (_Float16)u0.y;
            v[2] = (_Float16)u0.z; v[3] = (_Float16)u0.w;
            v[4] = (_Float16)u1.x; v[5] = (_Float16)u1.y;
            v[6] = (_Float16)u1.z; v[7] = (_Float16)u1.w;
        }
        *(f16x8*)&xs[row][coff] = v;
    }
    __syncthreads();
    if (tid < 64) {
        int lane = tid;
        int cl = lane & 15;
        int r0 = (lane >> 4) << 2;
        f32x4 ac = {0.f, 0.f, 0.f, 0.f};
        #pragma unroll
        for (int t = 0; t < 4; t++) {
            f16x8 av = *(const f16x8*)&xs[cl][t * 32 + ((lane >> 4) << 3)];
            f16x8 bv = *(const f16x8*)(waf + (size_t)t * 512 + (size_t)lane * 8);
            ac = __builtin_amdgcn_mfma_f32_16x16x32_f16(av, bv, ac, 0, 0, 0);
        }
        if (cl < 12) {
            #pragma unroll
            for (int reg = 0; reg < 4; reg++) {
                int node = base_node + r0 + reg;
                if (node < N) a0[(size_t)node * 12 + cl] = ac[reg];
            }
        }
    }
}

__device__ __forceinline__ float rlf(float v, int j) {
    return __int_as_float(__builtin_amdgcn_readlane(__float_as_int(v), j));
}

// per-wave: aggregate node n. No cross-lane reductions (r14): softmax without
// max-subtract (logits O(10), f32-exp safe; shift-invariant) and denominator
// accumulated from the readlane broadcasts (identical in all lanes).
__device__ __forceinline__ void aggregate_node(const float* __restrict__ x,
                                               const float* __restrict__ a,
                                               const int* __restrict__ rowend,
                                               const int* __restrict__ deg_,
                                               const int* __restrict__ col,
                                               int n, int lane,
                                               _Float16* __restrict__ xsrow) {
    const int deg = deg_[n];
    const int start = rowend[n] - deg;
    const int nent = deg + 1;

    float adst[H];
    #pragma unroll
    for (int h = 0; h < H; h++) adst[h] = a[(size_t)n * 12 + 6 + h];

    if (nent <= 64) {
        int s = n;                          // lane 'deg' = self loop
        if (lane < deg) s = col[start + lane];

        const float* as_ = a + (size_t)s * 12;
        float4 v0 = *(const float4*)as_;
        float2 v1 = *(const float2*)(as_ + 4);
        float e0 = v0.x + adst[0], e1 = v0.y + adst[1], e2 = v0.z + adst[2];
        float e3 = v0.w + adst[3], e4 = v1.x + adst[4], e5 = v1.y + adst[5];
        e0 = e0 > 0.f ? e0 : 0.2f * e0;  e1 = e1 > 0.f ? e1 : 0.2f * e1;
        e2 = e2 > 0.f ? e2 : 0.2f * e2;  e3 = e3 > 0.f ? e3 : 0.2f * e3;
        e4 = e4 > 0.f ? e4 : 0.2f * e4;  e5 = e5 > 0.f ? e5 : 0.2f * e5;
        float w0 = __expf(e0), w1 = __expf(e1), w2 = __expf(e2);
        float w3 = __expf(e3), w4 = __expf(e4), w5 = __expf(e5);

        float d0 = 0, d1 = 0, d2 = 0, d3 = 0, d4 = 0, d5 = 0;
        float a00 = 0, a01 = 0, a02 = 0, a03 = 0, a04 = 0, a05 = 0;
        float a10 = 0, a11 = 0, a12 = 0, a13 = 0, a14 = 0, a15 = 0;
        const float* xb = x + (lane << 1);   // channels c=2*lane, 2*lane+1

        float2 xa, xbv;
        {
            int s0 = __builtin_amdgcn_readlane(s, 0);
            xa = *(const float2*)(xb + (size_t)s0 * D);
        }
        xbv = make_float2(0.f, 0.f);
        if (nent > 1) {
            int s1 = __builtin_amdgcn_readlane(s, 1);
            xbv = *(const float2*)(xb + (size_t)s1 * D);
        }
        for (int j = 0; j < nent; j += 2) {
            float2 xn0 = make_float2(0.f, 0.f), xn1 = make_float2(0.f, 0.f);
            if (j + 2 < nent) {
                int s2 = __builtin_amdgcn_readlane(s, j + 2);
                xn0 = *(const float2*)(xb + (size_t)s2 * D);
            }
            if (j + 3 < nent) {
                int s3 = __builtin_amdgcn_readlane(s, j + 3);
                xn1 = *(const float2*)(xb + (size_t)s3 * D);
            }
            {
                float b0 = rlf(w0, j), b1 = rlf(w1, j), b2 = rlf(w2, j);
                float b3 = rlf(w3, j), b4 = rlf(w4, j), b5 = rlf(w5, j);
                d0 += b0; d1 += b1; d2 += b2; d3 += b3; d4 += b4; d5 += b5;
                a00 += b0 * xa.x; a10 += b0 * xa.y;
                a01 += b1 * xa.x; a11 += b1 * xa.y;
                a02 += b2 * xa.x; a12 += b2 * xa.y;
                a03 += b3 * xa.x; a13 += b3 * xa.y;
                a04 += b4 * xa.x; a14 += b4 * xa.y;
                a05 += b5 * xa.x; a15 += b5 * xa.y;
            }
            if (j + 1 < nent) {
                float b0 = rlf(w0, j + 1), b1 = rlf(w1, j + 1), b2 = rlf(w2, j + 1);
                float b3 = rlf(w3, j + 1), b4 = rlf(w4, j + 1), b5 = rlf(w5, j + 1);
                d0 += b0; d1 += b1; d2 += b2; d3 += b3; d4 += b4; d5 += b5;
                a00 += b0 * xbv.x; a10 += b0 * xbv.y;
                a01 += b1 * xbv.x; a11 += b1 * xbv.y;
                a02 += b2 * xbv.x; a12 += b2 * xbv.y;
                a03 += b3 * xbv.x; a13 += b3 * xbv.y;
                a04 += b4 * xbv.x; a14 += b4 * xbv.y;
                a05 += b5 * xbv.x; a15 += b5 * xbv.y;
            }
            xa = xn0; xbv = xn1;
        }
        float i0 = 1.f / d0, i1 = 1.f / d1, i2 = 1.f / d2;
        float i3 = 1.f / d3, i4 = 1.f / d4, i5 = 1.f / d5;
        int c = lane << 1;
        xsrow[0 * D + c] = (_Float16)(a00 * i0);  xsrow[0 * D + c + 1] = (_Float16)(a10 * i0);
        xsrow[1 * D + c] = (_Float16)(a01 * i1);  xsrow[1 * D + c + 1] = (_Float16)(a11 * i1);
        xsrow[2 * D + c] = (_Float16)(a02 * i2);  xsrow[2 * D + c + 1] = (_Float16)(a12 * i2);
        xsrow[3 * D + c] = (_Float16)(a03 * i3);  xsrow[3 * D + c + 1] = (_Float16)(a13 * i3);
        xsrow[4 * D + c] = (_Float16)(a04 * i4);  xsrow[4 * D + c + 1] = (_Float16)(a14 * i4);
        xsrow[5 * D + c] = (_Float16)(a05 * i5);  xsrow[5 * D + c + 1] = (_Float16)(a15 * i5);
    } else {
        // slow fallback (deg >= 64): single pass, no max-subtract
        float d[H] = {0, 0, 0, 0, 0, 0};
        float acc0[H] = {0, 0, 0, 0, 0, 0};
        float acc1[H] = {0, 0, 0, 0, 0, 0};
        int c0 = lane, c1 = 64 + lane;
        for (int j = 0; j <= deg; j++) {
            int s = (j < deg) ? col[start + j] : n;
            float w[H];
            #pragma unroll
            for (int h = 0; h < H; h++) {
                float e = a[(size_t)s * 12 + h] + adst[h];
                e = (e > 0.f) ? e : 0.2f * e;
                w[h] = __expf(e);
                d[h] += w[h];
            }
            float xv0 = x[(size_t)s * D + c0];
            float xv1 = x[(size_t)s * D + c1];
            #pragma unroll
            for (int h = 0; h < H; h++) {
                acc0[h] += w[h] * xv0;
                acc1[h] += w[h] * xv1;
            }
        }
        #pragma unroll
        for (int h = 0; h < H; h++) {
            float inv = 1.0f / d[h];
            xsrow[h * D + c0] = (_Float16)(acc0[h] * inv);
            xsrow[h * D + c1] = (_Float16)(acc1[h] * inv);
        }
    }
}

// ---------------- fused layer: aggregate(8 nodes -> LDS) + MFMA GEMM + a ----------------
__global__ __launch_bounds__(512) void layer_kernel(const float* __restrict__ x,
                                                    const float* __restrict__ a_in,
                                                    const int* __restrict__ rowend,
                                                    const int* __restrict__ deg_,
                                                    const int* __restrict__ col,
                                                    const _Float16* __restrict__ bf,
                                                    const float* __restrict__ bias,
                                                    float* __restrict__ xout,
                                                    const _Float16* __restrict__ awf,
                                                    float* __restrict__ a_out, int M) {
    __shared__ _Float16 xs16[16][PADK];   // rows 0..7 aggregated; 8..15 garbage
    __shared__ _Float16 xso[16][136];     // output rows (f16) for fused a
    const int wave = (int)(threadIdx.x >> 6);
    const int lane = (int)(threadIdx.x & 63);
    const int m0 = (int)(blockIdx.x << 3);

    // phase 1: each wave aggregates 1 node
    {
        int n = m0 + wave;
        if (n < M)
            aggregate_node(x, a_in, rowend, deg_, col, n, lane, &xs16[wave][0]);
    }
    __syncthreads();

    // phase 2: GEMM — wave w owns col-tile w (cols w*16..w*16+15)
    f32x4 acc = {0.f, 0.f, 0.f, 0.f};
    const _Float16* ars = &xs16[lane & 15][(lane >> 4) << 3];
    const _Float16* bp = bf + (size_t)wave * 512 + (size_t)lane * 8;
    for (int t = 0; t < TSTEPS; t++) {
        f16x8 av = *(const f16x8*)(ars + t * 32);
        f16x8 bv = *(const f16x8*)(bp + (size_t)t * 4096);
        acc = __builtin_amdgcn_mfma_f32_16x16x32_f16(av, bv, acc, 0, 0, 0);
    }

    const float inv6 = 1.0f / 6.0f;
    const int cl = lane & 15;
    const int ccol = wave * 16 + cl;
    const int r0 = (lane >> 4) << 2;
    const float bs = bias[ccol];
    #pragma unroll
    for (int reg = 0; reg < 4; reg++) {
        int ml = r0 + reg;
        int m = m0 + ml;
        float v = acc[reg] * inv6 + bs;
        v = v > 0.f ? v : 0.f;
        if (ml < NPB && m < M) xout[(size_t)m * D + ccol] = v;
        xso[ml][ccol] = (_Float16)v;
    }

    // phase 3: fused next-layer attention logits (wave 0)
    if (awf) {
        __syncthreads();
        if (wave == 0) {
            f32x4 ac = {0.f, 0.f, 0.f, 0.f};
            #pragma unroll
            for (int t = 0; t < 4; t++) {
                f16x8 av = *(const f16x8*)&xso[cl][t * 32 + ((lane >> 4) << 3)];
                f16x8 bv = *(const f16x8*)(awf + (size_t)t * 512 + (size_t)lane * 8);
                ac = __builtin_amdgcn_mfma_f32_16x16x32_f16(av, bv, ac, 0, 0, 0);
            }
            if (cl < 12) {
                #pragma unroll
                for (int reg = 0; reg < 4; reg++) {
                    int ml = r0 + reg;
                    int m = m0 + ml;
                    if (ml < NPB && m < M) a_out[(size_t)m * 12 + cl] = ac[reg];
                }
            }
        }
    }
}

// ---------------- host ----------------

extern "C" void kernel_launch(void* const* d_in, const int* in_sizes, int n_in,
                              void* d_out, int out_size, void* d_ws, size_t ws_size,
                              hipStream_t stream) {
    const float* x_in = (const float*)d_in[0];
    const int* ei = (const int*)d_in[1];
    int N = in_sizes[0] / D;
    int E = in_sizes[1] / 2;
    const int* srcp = ei;
    const int* dstp = ei + E;

    size_t bf_halves_per_layer = (size_t)TSTEPS * 8 * 512;   // 98304

    float* ws = (float*)d_ws;
    float* bufA = ws;
    float* bufB = bufA + (size_t)N * D;
    float* abuf0 = bufB + (size_t)N * D;
    float* abuf1 = abuf0 + (size_t)N * 12;
    float* wa_all = abuf1 + (size_t)N * 12;          // 4*1536 floats
    _Float16* waf = (_Float16*)(wa_all + 4 * 1536);  // 4 layers x 2048 halves
    _Float16* w16f = waf + 4 * 2048;
    int* deg = (int*)(w16f + 4 * bf_halves_per_layer);
    int* rowptr = deg + N;
    int* col = rowptr + (N + 1);

    FoldArgs fa;
    for (int l = 0; l < 4; l++) {
        fa.W[l]  = (const float*)d_in[2 + 4 * l];
        fa.as[l] = (const float*)d_in[3 + 4 * l];
        fa.ad[l] = (const float*)d_in[4 + 4 * l];
    }

    // CSR build + fused prep
    int n4 = (N + 3) / 4;
    zero_kernel<<<(n4 + 255) / 256, 256, 0, stream>>>((int4*)deg, n4);
    int histBlocks = (E + 255) / 256;
    hist_prep1_kernel<<<histBlocks + 24, 256, 0, stream>>>(dstp, deg, E, histBlocks, fa, wa_all);
    scan_kernel<<<1, 1024, 0, stream>>>(deg, rowptr, N, wa_all, waf);
    int scatBlocks = (E + 255) / 256;
    int a0Blocks = (N + 15) / 16;
    scatter_prep2_kernel<<<scatBlocks + 192 + a0Blocks, 256, 0, stream>>>(
        srcp, dstp, rowptr, col, E, scatBlocks, fa, waf, w16f, x_in, abuf0, N);

    const float* xcur = x_in;
    float* acur = abuf0;
    float* anext = abuf1;
    for (int l = 0; l < 4; l++) {
        const float* b = (const float*)d_in[5 + 4 * l];
        float* xout = (l == 3) ? (float*)d_out : ((l & 1) ? bufB : bufA);
        const _Float16* awf = (l < 3) ? (waf + (size_t)(l + 1) * 2048) : (const _Float16*)nullptr;

        layer_kernel<<<(N + NPB - 1) / NPB, 512, 0, stream>>>(xcur, acur, rowptr, deg, col,
                                                              w16f + (size_t)l * bf_halves_per_layer,
                                                              b, xout, awf, anext, N);
        xcur = xout;
        float* tmp = acur; acur = anext; anext = tmp;
    }
}

// Round 17
// 140.441 us; speedup vs baseline: 1.3998x; 1.1607x over previous
//
#include <hip/hip_runtime.h>
#include <hip/hip_fp16.h>
#include <math.h>

#define H 6
#define D 128
#define K_ALL (H * D)   // 768
#define TSTEPS 24       // K_ALL / 32
#define PADK 776        // 768 + 8 halves pad -> conflict-free fragment reads
#define NPB 8           // nodes per block (1 per wave)
#define BSTRIDE 128     // fixed col-bucket capacity per node

typedef _Float16 f16x8 __attribute__((ext_vector_type(8)));
typedef float f32x4 __attribute__((ext_vector_type(4)));

struct FoldArgs {
    const float* W[4];
    const float* as[4];
    const float* ad[4];
};

// ---------------- K1: zero deg + wa_all dots ----------------

__global__ __launch_bounds__(256) void zero_wa_kernel(int4* __restrict__ degz, int n4,
                                                      int zBlocks, FoldArgs fa,
                                                      float* __restrict__ wa_all) {
    int b = blockIdx.x;
    int tid = threadIdx.x;
    if (b < zBlocks) {
        int i = b * 256 + tid;
        if (i < n4) degz[i] = make_int4(0, 0, 0, 0);
        return;
    }
    int t = (b - zBlocks) * 256 + tid;   // < 6144
    if (t >= 4 * 1536) return;
    int l = t / 1536;
    int r = t % 1536;
    int k = r / 12, j = r % 12;
    int h = (j < 6) ? j : (j - 6);
    const float* att = (j < 6) ? fa.as[l] : fa.ad[l];
    const float* wrow = fa.W[l] + (size_t)k * K_ALL + h * D;
    const float* arow = att + h * D;
    float s = 0.f;
    #pragma unroll 8
    for (int c = 0; c < D; c++) s += wrow[c] * arow[c];
    wa_all[(size_t)l * 1536 + k * 12 + j] = s;
}

// ---------------- K2: scatter-hist | bf pack | waf pack | layer-0 a ----------------
// NOTE: the a0-MFMA blocks build their L0 B-fragments inline from wa_all
// (written in K1 -> cross-dispatch safe). They must NOT read waf, which is
// packed by other blocks of THIS dispatch (intra-dispatch order undefined —
// that race was round 16's failure).

__global__ __launch_bounds__(256) void prep2_kernel(const int* __restrict__ src,
                                                    const int* __restrict__ dst,
                                                    int* __restrict__ deg,
                                                    int* __restrict__ col, int E,
                                                    int scatBlocks, FoldArgs fa,
                                                    const float* __restrict__ wa_all,
                                                    _Float16* __restrict__ waf,
                                                    _Float16* __restrict__ bf,
                                                    const float* __restrict__ x_in,
                                                    float* __restrict__ a0, int N) {
    __shared__ _Float16 xs[16][136];
    int b = blockIdx.x;
    int tid = threadIdx.x;
    if (b < scatBlocks) {
        // combined histogram + bucket scatter (one pass over E)
        int e = b * 256 + tid;
        if (e < E) {
            int n = dst[e];
            int p = atomicAdd(&deg[n], 1);
            if (p < BSTRIDE) col[(size_t)n * BSTRIDE + p] = src[e];
        }
        return;
    }
    int bb = b - scatBlocks;
    if (bb < 192) {
        int idx = bb * 256 + tid;    // < 49152
        int l63 = idx & 63;
        int ct = (idx >> 6) & 7;
        int t = (idx >> 9) % TSTEPS;
        int layer = idx / (TSTEPS * 8 * 64);
        const float* W = fa.W[layer];
        int c = ct * 16 + (l63 & 15);
        f16x8 v;
        #pragma unroll
        for (int j = 0; j < 8; j++) {
            int k = t * 32 + ((l63 >> 4) << 3) + j;
            v[j] = (_Float16)W[(size_t)(k & 127) * K_ALL + ((k >> 7) << 7) + c];
        }
        *(f16x8*)(bf + ((size_t)idx << 3)) = v;
        return;
    }
    bb -= 192;
    if (bb < 4) {
        // waf fragment pack for layer L = bb (consumed by layer_kernel, next dispatch)
        int L = bb;
        int lane = tid & 63;
        int t = tid >> 6;
        int j = lane & 15;
        const float* wl = wa_all + (size_t)L * 1536;
        f16x8 vv;
        #pragma unroll
        for (int jj = 0; jj < 8; jj++) {
            int k = t * 32 + ((lane >> 4) << 3) + jj;
            float sv = (j < 12) ? wl[k * 12 + j] : 0.f;
            vv[jj] = (_Float16)sv;
        }
        *(f16x8*)(waf + (size_t)L * 2048 + (size_t)t * 512 + (size_t)lane * 8) = vv;
        return;
    }
    bb -= 4;
    // layer-0 a via MFMA: 16 nodes per block
    int base_node = bb << 4;
    {
        int row = tid >> 4;                 // 0..15
        int coff = (tid & 15) * 8;          // 0..120
        int node = base_node + row;
        f16x8 v = {};
        if (node < N) {
            const float* sp = x_in + (size_t)node * D + coff;
            float4 u0 = *(const float4*)sp;
            float4 u1 = *(const float4*)(sp + 4);
            v[0] = (_Float16)u0.x; v[1] = (_Float16)u0.y;
            v[2] = (_Float16)u0.z; v[3] = (_Float16)u0.w;
            v[4] = (_Float16)u1.x; v[5] = (_Float16)u1.y;
            v[6] = (_Float16)u1.z; v[7] = (_Float16)u1.w;
        }
        *(f16x8*)&xs[row][coff] = v;
    }
    __syncthreads();
    if (tid < 64) {
        int lane = tid;
        int cl = lane & 15;
        int r0 = (lane >> 4) << 2;
        const float* wl0 = wa_all;   // layer 0, from K1 (safe)
        f32x4 ac = {0.f, 0.f, 0.f, 0.f};
        #pragma unroll
        for (int t = 0; t < 4; t++) {
            f16x8 av = *(const f16x8*)&xs[cl][t * 32 + ((lane >> 4) << 3)];
            f16x8 bv;
            #pragma unroll
            for (int jj = 0; jj < 8; jj++) {
                int k = t * 32 + ((lane >> 4) << 3) + jj;
                float sv = (cl < 12) ? wl0[k * 12 + cl] : 0.f;
                bv[jj] = (_Float16)sv;
            }
            ac = __builtin_amdgcn_mfma_f32_16x16x32_f16(av, bv, ac, 0, 0, 0);
        }
        if (cl < 12) {
            #pragma unroll
            for (int reg = 0; reg < 4; reg++) {
                int node = base_node + r0 + reg;
                if (node < N) a0[(size_t)node * 12 + cl] = ac[reg];
            }
        }
    }
}

__device__ __forceinline__ float rlf(float v, int j) {
    return __int_as_float(__builtin_amdgcn_readlane(__float_as_int(v), j));
}

// per-wave: aggregate node n from its fixed-stride bucket col[n*128 ...].
// No cross-lane reductions (r14): softmax without max-subtract (logits O(10),
// f32-exp safe; shift-invariant); denominator from readlane broadcasts.
__device__ __forceinline__ void aggregate_node(const float* __restrict__ x,
                                               const float* __restrict__ a,
                                               const int* __restrict__ deg_,
                                               const int* __restrict__ col,
                                               int n, int lane,
                                               _Float16* __restrict__ xsrow) {
    const int deg = deg_[n];
    const int start = n << 7;   // BSTRIDE = 128
    const int nent = deg + 1;

    float adst[H];
    #pragma unroll
    for (int h = 0; h < H; h++) adst[h] = a[(size_t)n * 12 + 6 + h];

    if (nent <= 64) {
        int s = n;                          // lane 'deg' = self loop
        if (lane < deg) s = col[start + lane];

        const float* as_ = a + (size_t)s * 12;
        float4 v0 = *(const float4*)as_;
        float2 v1 = *(const float2*)(as_ + 4);
        float e0 = v0.x + adst[0], e1 = v0.y + adst[1], e2 = v0.z + adst[2];
        float e3 = v0.w + adst[3], e4 = v1.x + adst[4], e5 = v1.y + adst[5];
        e0 = e0 > 0.f ? e0 : 0.2f * e0;  e1 = e1 > 0.f ? e1 : 0.2f * e1;
        e2 = e2 > 0.f ? e2 : 0.2f * e2;  e3 = e3 > 0.f ? e3 : 0.2f * e3;
        e4 = e4 > 0.f ? e4 : 0.2f * e4;  e5 = e5 > 0.f ? e5 : 0.2f * e5;
        float w0 = __expf(e0), w1 = __expf(e1), w2 = __expf(e2);
        float w3 = __expf(e3), w4 = __expf(e4), w5 = __expf(e5);

        float d0 = 0, d1 = 0, d2 = 0, d3 = 0, d4 = 0, d5 = 0;
        float a00 = 0, a01 = 0, a02 = 0, a03 = 0, a04 = 0, a05 = 0;
        float a10 = 0, a11 = 0, a12 = 0, a13 = 0, a14 = 0, a15 = 0;
        const float* xb = x + (lane << 1);   // channels c=2*lane, 2*lane+1

        float2 xa, xbv;
        {
            int s0 = __builtin_amdgcn_readlane(s, 0);
            xa = *(const float2*)(xb + (size_t)s0 * D);
        }
        xbv = make_float2(0.f, 0.f);
        if (nent > 1) {
            int s1 = __builtin_amdgcn_readlane(s, 1);
            xbv = *(const float2*)(xb + (size_t)s1 * D);
        }
        for (int j = 0; j < nent; j += 2) {
            float2 xn0 = make_float2(0.f, 0.f), xn1 = make_float2(0.f, 0.f);
            if (j + 2 < nent) {
                int s2 = __builtin_amdgcn_readlane(s, j + 2);
                xn0 = *(const float2*)(xb + (size_t)s2 * D);
            }
            if (j + 3 < nent) {
                int s3 = __builtin_amdgcn_readlane(s, j + 3);
                xn1 = *(const float2*)(xb + (size_t)s3 * D);
            }
            {
                float b0 = rlf(w0, j), b1 = rlf(w1, j), b2 = rlf(w2, j);
                float b3 = rlf(w3, j), b4 = rlf(w4, j), b5 = rlf(w5, j);
                d0 += b0; d1 += b1; d2 += b2; d3 += b3; d4 += b4; d5 += b5;
                a00 += b0 * xa.x; a10 += b0 * xa.y;
                a01 += b1 * xa.x; a11 += b1 * xa.y;
                a02 += b2 * xa.x; a12 += b2 * xa.y;
                a03 += b3 * xa.x; a13 += b3 * xa.y;
                a04 += b4 * xa.x; a14 += b4 * xa.y;
                a05 += b5 * xa.x; a15 += b5 * xa.y;
            }
            if (j + 1 < nent) {
                float b0 = rlf(w0, j + 1), b1 = rlf(w1, j + 1), b2 = rlf(w2, j + 1);
                float b3 = rlf(w3, j + 1), b4 = rlf(w4, j + 1), b5 = rlf(w5, j + 1);
                d0 += b0; d1 += b1; d2 += b2; d3 += b3; d4 += b4; d5 += b5;
                a00 += b0 * xbv.x; a10 += b0 * xbv.y;
                a01 += b1 * xbv.x; a11 += b1 * xbv.y;
                a02 += b2 * xbv.x; a12 += b2 * xbv.y;
                a03 += b3 * xbv.x; a13 += b3 * xbv.y;
                a04 += b4 * xbv.x; a14 += b4 * xbv.y;
                a05 += b5 * xbv.x; a15 += b5 * xbv.y;
            }
            xa = xn0; xbv = xn1;
        }
        float i0 = 1.f / d0, i1 = 1.f / d1, i2 = 1.f / d2;
        float i3 = 1.f / d3, i4 = 1.f / d4, i5 = 1.f / d5;
        int c = lane << 1;
        xsrow[0 * D + c] = (_Float16)(a00 * i0);  xsrow[0 * D + c + 1] = (_Float16)(a10 * i0);
        xsrow[1 * D + c] = (_Float16)(a01 * i1);  xsrow[1 * D + c + 1] = (_Float16)(a11 * i1);
        xsrow[2 * D + c] = (_Float16)(a02 * i2);  xsrow[2 * D + c + 1] = (_Float16)(a12 * i2);
        xsrow[3 * D + c] = (_Float16)(a03 * i3);  xsrow[3 * D + c + 1] = (_Float16)(a13 * i3);
        xsrow[4 * D + c] = (_Float16)(a04 * i4);  xsrow[4 * D + c + 1] = (_Float16)(a14 * i4);
        xsrow[5 * D + c] = (_Float16)(a05 * i5);  xsrow[5 * D + c + 1] = (_Float16)(a15 * i5);
    } else {
        // slow fallback (64 <= deg): single pass, no max-subtract.
        int dl = deg < BSTRIDE ? deg : BSTRIDE;
        float d[H] = {0, 0, 0, 0, 0, 0};
        float acc0[H] = {0, 0, 0, 0, 0, 0};
        float acc1[H] = {0, 0, 0, 0, 0, 0};
        int c0 = lane, c1 = 64 + lane;
        for (int j = 0; j <= dl; j++) {
            int s = (j < dl) ? col[start + j] : n;
            float w[H];
            #pragma unroll
            for (int h = 0; h < H; h++) {
                float e = a[(size_t)s * 12 + h] + adst[h];
                e = (e > 0.f) ? e : 0.2f * e;
                w[h] = __expf(e);
                d[h] += w[h];
            }
            float xv0 = x[(size_t)s * D + c0];
            float xv1 = x[(size_t)s * D + c1];
            #pragma unroll
            for (int h = 0; h < H; h++) {
                acc0[h] += w[h] * xv0;
                acc1[h] += w[h] * xv1;
            }
        }
        #pragma unroll
        for (int h = 0; h < H; h++) {
            float inv = 1.0f / d[h];
            xsrow[h * D + c0] = (_Float16)(acc0[h] * inv);
            xsrow[h * D + c1] = (_Float16)(acc1[h] * inv);
        }
    }
}

// ---------------- fused layer: aggregate(8 nodes -> LDS) + MFMA GEMM + a ----------------
__global__ __launch_bounds__(512) void layer_kernel(const float* __restrict__ x,
                                                    const float* __restrict__ a_in,
                                                    const int* __restrict__ deg_,
                                                    const int* __restrict__ col,
                                                    const _Float16* __restrict__ bf,
                                                    const float* __restrict__ bias,
                                                    float* __restrict__ xout,
                                                    const _Float16* __restrict__ awf,
                                                    float* __restrict__ a_out, int M) {
    __shared__ _Float16 xs16[16][PADK];   // rows 0..7 aggregated; 8..15 garbage
    __shared__ _Float16 xso[16][136];     // output rows (f16) for fused a
    const int wave = (int)(threadIdx.x >> 6);
    const int lane = (int)(threadIdx.x & 63);
    const int m0 = (int)(blockIdx.x << 3);

    // phase 1: each wave aggregates 1 node
    {
        int n = m0 + wave;
        if (n < M)
            aggregate_node(x, a_in, deg_, col, n, lane, &xs16[wave][0]);
    }
    __syncthreads();

    // phase 2: GEMM — wave w owns col-tile w (cols w*16..w*16+15)
    f32x4 acc = {0.f, 0.f, 0.f, 0.f};
    const _Float16* ars = &xs16[lane & 15][(lane >> 4) << 3];
    const _Float16* bp = bf + (size_t)wave * 512 + (size_t)lane * 8;
    for (int t = 0; t < TSTEPS; t++) {
        f16x8 av = *(const f16x8*)(ars + t * 32);
        f16x8 bv = *(const f16x8*)(bp + (size_t)t * 4096);
        acc = __builtin_amdgcn_mfma_f32_16x16x32_f16(av, bv, acc, 0, 0, 0);
    }

    const float inv6 = 1.0f / 6.0f;
    const int cl = lane & 15;
    const int ccol = wave * 16 + cl;
    const int r0 = (lane >> 4) << 2;
    const float bs = bias[ccol];
    #pragma unroll
    for (int reg = 0; reg < 4; reg++) {
        int ml = r0 + reg;
        int m = m0 + ml;
        float v = acc[reg] * inv6 + bs;
        v = v > 0.f ? v : 0.f;
        if (ml < NPB && m < M) xout[(size_t)m * D + ccol] = v;
        xso[ml][ccol] = (_Float16)v;
    }

    // phase 3: fused next-layer attention logits (wave 0)
    if (awf) {
        __syncthreads();
        if (wave == 0) {
            f32x4 ac = {0.f, 0.f, 0.f, 0.f};
            #pragma unroll
            for (int t = 0; t < 4; t++) {
                f16x8 av = *(const f16x8*)&xso[cl][t * 32 + ((lane >> 4) << 3)];
                f16x8 bv = *(const f16x8*)(awf + (size_t)t * 512 + (size_t)lane * 8);
                ac = __builtin_amdgcn_mfma_f32_16x16x32_f16(av, bv, ac, 0, 0, 0);
            }
            if (cl < 12) {
                #pragma unroll
                for (int reg = 0; reg < 4; reg++) {
                    int ml = r0 + reg;
                    int m = m0 + ml;
                    if (ml < NPB && m < M) a_out[(size_t)m * 12 + cl] = ac[reg];
                }
            }
        }
    }
}

// ---------------- host ----------------

extern "C" void kernel_launch(void* const* d_in, const int* in_sizes, int n_in,
                              void* d_out, int out_size, void* d_ws, size_t ws_size,
                              hipStream_t stream) {
    const float* x_in = (const float*)d_in[0];
    const int* ei = (const int*)d_in[1];
    int N = in_sizes[0] / D;
    int E = in_sizes[1] / 2;
    const int* srcp = ei;
    const int* dstp = ei + E;

    size_t bf_halves_per_layer = (size_t)TSTEPS * 8 * 512;   // 98304

    float* ws = (float*)d_ws;
    float* bufA = ws;
    float* bufB = bufA + (size_t)N * D;
    float* abuf0 = bufB + (size_t)N * D;
    float* abuf1 = abuf0 + (size_t)N * 12;
    float* wa_all = abuf1 + (size_t)N * 12;          // 4*1536 floats
    _Float16* waf = (_Float16*)(wa_all + 4 * 1536);  // 4 layers x 2048 halves
    _Float16* w16f = waf + 4 * 2048;
    int* deg = (int*)(w16f + 4 * bf_halves_per_layer);
    int* col = deg + N;                               // N * BSTRIDE ints

    FoldArgs fa;
    for (int l = 0; l < 4; l++) {
        fa.W[l]  = (const float*)d_in[2 + 4 * l];
        fa.as[l] = (const float*)d_in[3 + 4 * l];
        fa.ad[l] = (const float*)d_in[4 + 4 * l];
    }

    // K1: zero deg + wa_all dots
    int n4 = (N + 3) / 4;
    int zBlocks = (n4 + 255) / 256;
    zero_wa_kernel<<<zBlocks + 24, 256, 0, stream>>>((int4*)deg, n4, zBlocks, fa, wa_all);

    // K2: scatter-hist | bf pack | waf pack | layer-0 a
    int scatBlocks = (E + 255) / 256;
    int a0Blocks = (N + 15) / 16;
    prep2_kernel<<<scatBlocks + 192 + 4 + a0Blocks, 256, 0, stream>>>(
        srcp, dstp, deg, col, E, scatBlocks, fa, wa_all, waf, w16f, x_in, abuf0, N);

    const float* xcur = x_in;
    float* acur = abuf0;
    float* anext = abuf1;
    for (int l = 0; l < 4; l++) {
        const float* b = (const float*)d_in[5 + 4 * l];
        float* xout = (l == 3) ? (float*)d_out : ((l & 1) ? bufB : bufA);
        const _Float16* awf = (l < 3) ? (waf + (size_t)(l + 1) * 2048) : (const _Float16*)nullptr;

        layer_kernel<<<(N + NPB - 1) / NPB, 512, 0, stream>>>(xcur, acur, deg, col,
                                                              w16f + (size_t)l * bf_halves_per_layer,
                                                              b, xout, awf, anext, N);
        xcur = xout;
        float* tmp = acur; acur = anext; anext = tmp;
    }
}

// Round 18
// 130.727 us; speedup vs baseline: 1.5038x; 1.0743x over previous
//
#include <hip/hip_runtime.h>
#include <hip/hip_fp16.h>
#include <math.h>

#define H 6
#define D 128
#define K_ALL (H * D)   // 768
#define TSTEPS 24       // K_ALL / 32
#define PADK 776        // 768 + 8 halves pad -> conflict-free fragment reads
#define NPB 8           // nodes per block (1 per wave)
#define BSTRIDE 128     // fixed col-bucket capacity per node

typedef _Float16 f16x8 __attribute__((ext_vector_type(8)));
typedef float f32x4 __attribute__((ext_vector_type(4)));

struct FoldArgs {
    const float* W[4];
    const float* as[4];
    const float* ad[4];
};

// ---------------- K1: zero deg + wa_all dots ----------------

__global__ __launch_bounds__(256) void zero_wa_kernel(int4* __restrict__ degz, int n4,
                                                      int zBlocks, FoldArgs fa,
                                                      float* __restrict__ wa_all) {
    int b = blockIdx.x;
    int tid = threadIdx.x;
    if (b < zBlocks) {
        int i = b * 256 + tid;
        if (i < n4) degz[i] = make_int4(0, 0, 0, 0);
        return;
    }
    int t = (b - zBlocks) * 256 + tid;   // < 6144
    if (t >= 4 * 1536) return;
    int l = t / 1536;
    int r = t % 1536;
    int k = r / 12, j = r % 12;
    int h = (j < 6) ? j : (j - 6);
    const float* att = (j < 6) ? fa.as[l] : fa.ad[l];
    const float* wrow = fa.W[l] + (size_t)k * K_ALL + h * D;
    const float* arow = att + h * D;
    float s = 0.f;
    #pragma unroll 8
    for (int c = 0; c < D; c++) s += wrow[c] * arow[c];
    wa_all[(size_t)l * 1536 + k * 12 + j] = s;
}

// ---------------- K2: scatter-hist | bf pack | waf pack | layer-0 a ----------------
// a0-MFMA blocks build their L0 B-fragments inline from wa_all (K1 -> safe);
// they must NOT read waf (packed by other blocks of THIS dispatch — r16 race).

__global__ __launch_bounds__(256) void prep2_kernel(const int* __restrict__ src,
                                                    const int* __restrict__ dst,
                                                    int* __restrict__ deg,
                                                    int* __restrict__ col, int E,
                                                    int scatBlocks, FoldArgs fa,
                                                    const float* __restrict__ wa_all,
                                                    _Float16* __restrict__ waf,
                                                    _Float16* __restrict__ bf,
                                                    const float* __restrict__ x_in,
                                                    float* __restrict__ a0, int N) {
    __shared__ _Float16 xs[16][136];
    int b = blockIdx.x;
    int tid = threadIdx.x;
    if (b < scatBlocks) {
        int e = b * 256 + tid;
        if (e < E) {
            int n = dst[e];
            int p = atomicAdd(&deg[n], 1);
            if (p < BSTRIDE) col[(size_t)n * BSTRIDE + p] = src[e];
        }
        return;
    }
    int bb = b - scatBlocks;
    if (bb < 192) {
        int idx = bb * 256 + tid;    // < 49152
        int l63 = idx & 63;
        int ct = (idx >> 6) & 7;
        int t = (idx >> 9) % TSTEPS;
        int layer = idx / (TSTEPS * 8 * 64);
        const float* W = fa.W[layer];
        int c = ct * 16 + (l63 & 15);
        f16x8 v;
        #pragma unroll
        for (int j = 0; j < 8; j++) {
            int k = t * 32 + ((l63 >> 4) << 3) + j;
            v[j] = (_Float16)W[(size_t)(k & 127) * K_ALL + ((k >> 7) << 7) + c];
        }
        *(f16x8*)(bf + ((size_t)idx << 3)) = v;
        return;
    }
    bb -= 192;
    if (bb < 4) {
        int L = bb;
        int lane = tid & 63;
        int t = tid >> 6;
        int j = lane & 15;
        const float* wl = wa_all + (size_t)L * 1536;
        f16x8 vv;
        #pragma unroll
        for (int jj = 0; jj < 8; jj++) {
            int k = t * 32 + ((lane >> 4) << 3) + jj;
            float sv = (j < 12) ? wl[k * 12 + j] : 0.f;
            vv[jj] = (_Float16)sv;
        }
        *(f16x8*)(waf + (size_t)L * 2048 + (size_t)t * 512 + (size_t)lane * 8) = vv;
        return;
    }
    bb -= 4;
    // layer-0 a via MFMA: 16 nodes per block
    int base_node = bb << 4;
    {
        int row = tid >> 4;
        int coff = (tid & 15) * 8;
        int node = base_node + row;
        f16x8 v = {};
        if (node < N) {
            const float* sp = x_in + (size_t)node * D + coff;
            float4 u0 = *(const float4*)sp;
            float4 u1 = *(const float4*)(sp + 4);
            v[0] = (_Float16)u0.x; v[1] = (_Float16)u0.y;
            v[2] = (_Float16)u0.z; v[3] = (_Float16)u0.w;
            v[4] = (_Float16)u1.x; v[5] = (_Float16)u1.y;
            v[6] = (_Float16)u1.z; v[7] = (_Float16)u1.w;
        }
        *(f16x8*)&xs[row][coff] = v;
    }
    __syncthreads();
    if (tid < 64) {
        int lane = tid;
        int cl = lane & 15;
        int r0 = (lane >> 4) << 2;
        const float* wl0 = wa_all;
        f32x4 ac = {0.f, 0.f, 0.f, 0.f};
        #pragma unroll
        for (int t = 0; t < 4; t++) {
            f16x8 av = *(const f16x8*)&xs[cl][t * 32 + ((lane >> 4) << 3)];
            f16x8 bv;
            #pragma unroll
            for (int jj = 0; jj < 8; jj++) {
                int k = t * 32 + ((lane >> 4) << 3) + jj;
                float sv = (cl < 12) ? wl0[k * 12 + cl] : 0.f;
                bv[jj] = (_Float16)sv;
            }
            ac = __builtin_amdgcn_mfma_f32_16x16x32_f16(av, bv, ac, 0, 0, 0);
        }
        if (cl < 12) {
            #pragma unroll
            for (int reg = 0; reg < 4; reg++) {
                int node = base_node + r0 + reg;
                if (node < N) a0[(size_t)node * 12 + cl] = ac[reg];
            }
        }
    }
}

__device__ __forceinline__ float rlf(float v, int j) {
    return __int_as_float(__builtin_amdgcn_readlane(__float_as_int(v), j));
}

// per-wave: aggregate node n from its fixed-stride bucket col[n*128 ...].
// r14: no cross-lane reductions. r18: x-prefetch issued IMMEDIATELY after the
// col read (depends only on s), overlapping the a-gather+exp head latency;
// 3-pair rotation keeps ~6 loads in flight (use issued 2 iterations ahead).
__device__ __forceinline__ void aggregate_node(const float* __restrict__ x,
                                               const float* __restrict__ a,
                                               const int* __restrict__ deg_,
                                               const int* __restrict__ col,
                                               int n, int lane,
                                               _Float16* __restrict__ xsrow) {
    const int deg = deg_[n];
    const int start = n << 7;   // BSTRIDE = 128
    const int nent = deg + 1;

    if (nent <= 64) {
        int s = n;                          // lane 'deg' = self loop
        if (lane < deg) s = col[start + lane];

        // ---- x prefetch head: depends only on s ----
        const float* xb = x + (lane << 1);   // channels c=2*lane, 2*lane+1
        float2 cur0, cur1, nxt0, nxt1;
        {
            int t0 = __builtin_amdgcn_readlane(s, 0);
            cur0 = *(const float2*)(xb + (size_t)t0 * D);
        }
        cur1 = make_float2(0.f, 0.f);
        nxt0 = make_float2(0.f, 0.f);
        nxt1 = make_float2(0.f, 0.f);
        if (nent > 1) {
            int t1 = __builtin_amdgcn_readlane(s, 1);
            cur1 = *(const float2*)(xb + (size_t)t1 * D);
        }
        if (nent > 2) {
            int t2 = __builtin_amdgcn_readlane(s, 2);
            nxt0 = *(const float2*)(xb + (size_t)t2 * D);
        }
        if (nent > 3) {
            int t3 = __builtin_amdgcn_readlane(s, 3);
            nxt1 = *(const float2*)(xb + (size_t)t3 * D);
        }

        // ---- logits + exp (overlaps the prefetch latency) ----
        float adst[H];
        #pragma unroll
        for (int h = 0; h < H; h++) adst[h] = a[(size_t)n * 12 + 6 + h];
        const float* as_ = a + (size_t)s * 12;
        float4 v0 = *(const float4*)as_;
        float2 v1 = *(const float2*)(as_ + 4);
        float e0 = v0.x + adst[0], e1 = v0.y + adst[1], e2 = v0.z + adst[2];
        float e3 = v0.w + adst[3], e4 = v1.x + adst[4], e5 = v1.y + adst[5];
        e0 = e0 > 0.f ? e0 : 0.2f * e0;  e1 = e1 > 0.f ? e1 : 0.2f * e1;
        e2 = e2 > 0.f ? e2 : 0.2f * e2;  e3 = e3 > 0.f ? e3 : 0.2f * e3;
        e4 = e4 > 0.f ? e4 : 0.2f * e4;  e5 = e5 > 0.f ? e5 : 0.2f * e5;
        float w0 = __expf(e0), w1 = __expf(e1), w2 = __expf(e2);
        float w3 = __expf(e3), w4 = __expf(e4), w5 = __expf(e5);

        float d0 = 0, d1 = 0, d2 = 0, d3 = 0, d4 = 0, d5 = 0;
        float a00 = 0, a01 = 0, a02 = 0, a03 = 0, a04 = 0, a05 = 0;
        float a10 = 0, a11 = 0, a12 = 0, a13 = 0, a14 = 0, a15 = 0;

        for (int j = 0; j < nent; j += 2) {
            float2 fut0 = make_float2(0.f, 0.f), fut1 = make_float2(0.f, 0.f);
            if (j + 4 < nent) {
                int t = __builtin_amdgcn_readlane(s, j + 4);
                fut0 = *(const float2*)(xb + (size_t)t * D);
            }
            if (j + 5 < nent) {
                int t = __builtin_amdgcn_readlane(s, j + 5);
                fut1 = *(const float2*)(xb + (size_t)t * D);
            }
            {
                float b0 = rlf(w0, j), b1 = rlf(w1, j), b2 = rlf(w2, j);
                float b3 = rlf(w3, j), b4 = rlf(w4, j), b5 = rlf(w5, j);
                d0 += b0; d1 += b1; d2 += b2; d3 += b3; d4 += b4; d5 += b5;
                a00 += b0 * cur0.x; a10 += b0 * cur0.y;
                a01 += b1 * cur0.x; a11 += b1 * cur0.y;
                a02 += b2 * cur0.x; a12 += b2 * cur0.y;
                a03 += b3 * cur0.x; a13 += b3 * cur0.y;
                a04 += b4 * cur0.x; a14 += b4 * cur0.y;
                a05 += b5 * cur0.x; a15 += b5 * cur0.y;
            }
            if (j + 1 < nent) {
                float b0 = rlf(w0, j + 1), b1 = rlf(w1, j + 1), b2 = rlf(w2, j + 1);
                float b3 = rlf(w3, j + 1), b4 = rlf(w4, j + 1), b5 = rlf(w5, j + 1);
                d0 += b0; d1 += b1; d2 += b2; d3 += b3; d4 += b4; d5 += b5;
                a00 += b0 * cur1.x; a10 += b0 * cur1.y;
                a01 += b1 * cur1.x; a11 += b1 * cur1.y;
                a02 += b2 * cur1.x; a12 += b2 * cur1.y;
                a03 += b3 * cur1.x; a13 += b3 * cur1.y;
                a04 += b4 * cur1.x; a14 += b4 * cur1.y;
                a05 += b5 * cur1.x; a15 += b5 * cur1.y;
            }
            cur0 = nxt0; cur1 = nxt1;
            nxt0 = fut0; nxt1 = fut1;
        }
        float i0 = 1.f / d0, i1 = 1.f / d1, i2 = 1.f / d2;
        float i3 = 1.f / d3, i4 = 1.f / d4, i5 = 1.f / d5;
        int c = lane << 1;
        xsrow[0 * D + c] = (_Float16)(a00 * i0);  xsrow[0 * D + c + 1] = (_Float16)(a10 * i0);
        xsrow[1 * D + c] = (_Float16)(a01 * i1);  xsrow[1 * D + c + 1] = (_Float16)(a11 * i1);
        xsrow[2 * D + c] = (_Float16)(a02 * i2);  xsrow[2 * D + c + 1] = (_Float16)(a12 * i2);
        xsrow[3 * D + c] = (_Float16)(a03 * i3);  xsrow[3 * D + c + 1] = (_Float16)(a13 * i3);
        xsrow[4 * D + c] = (_Float16)(a04 * i4);  xsrow[4 * D + c + 1] = (_Float16)(a14 * i4);
        xsrow[5 * D + c] = (_Float16)(a05 * i5);  xsrow[5 * D + c + 1] = (_Float16)(a15 * i5);
    } else {
        // slow fallback (64 <= deg): single pass, no max-subtract.
        float adst[H];
        #pragma unroll
        for (int h = 0; h < H; h++) adst[h] = a[(size_t)n * 12 + 6 + h];
        int dl = deg < BSTRIDE ? deg : BSTRIDE;
        float d[H] = {0, 0, 0, 0, 0, 0};
        float acc0[H] = {0, 0, 0, 0, 0, 0};
        float acc1[H] = {0, 0, 0, 0, 0, 0};
        int c0 = lane, c1 = 64 + lane;
        for (int j = 0; j <= dl; j++) {
            int s = (j < dl) ? col[start + j] : n;
            float w[H];
            #pragma unroll
            for (int h = 0; h < H; h++) {
                float e = a[(size_t)s * 12 + h] + adst[h];
                e = (e > 0.f) ? e : 0.2f * e;
                w[h] = __expf(e);
                d[h] += w[h];
            }
            float xv0 = x[(size_t)s * D + c0];
            float xv1 = x[(size_t)s * D + c1];
            #pragma unroll
            for (int h = 0; h < H; h++) {
                acc0[h] += w[h] * xv0;
                acc1[h] += w[h] * xv1;
            }
        }
        #pragma unroll
        for (int h = 0; h < H; h++) {
            float inv = 1.0f / d[h];
            xsrow[h * D + c0] = (_Float16)(acc0[h] * inv);
            xsrow[h * D + c1] = (_Float16)(acc1[h] * inv);
        }
    }
}

// ---------------- fused layer: aggregate(8 nodes -> LDS) + MFMA GEMM + a ----------------
__global__ __launch_bounds__(512) void layer_kernel(const float* __restrict__ x,
                                                    const float* __restrict__ a_in,
                                                    const int* __restrict__ deg_,
                                                    const int* __restrict__ col,
                                                    const _Float16* __restrict__ bf,
                                                    const float* __restrict__ bias,
                                                    float* __restrict__ xout,
                                                    const _Float16* __restrict__ awf,
                                                    float* __restrict__ a_out, int M) {
    __shared__ _Float16 xs16[16][PADK];   // rows 0..7 aggregated; 8..15 garbage
    __shared__ _Float16 xso[16][136];     // output rows (f16) for fused a
    const int wave = (int)(threadIdx.x >> 6);
    const int lane = (int)(threadIdx.x & 63);
    const int m0 = (int)(blockIdx.x << 3);

    // phase 1: each wave aggregates 1 node
    {
        int n = m0 + wave;
        if (n < M)
            aggregate_node(x, a_in, deg_, col, n, lane, &xs16[wave][0]);
    }
    __syncthreads();

    // phase 2: GEMM — wave w owns col-tile w (cols w*16..w*16+15)
    f32x4 acc = {0.f, 0.f, 0.f, 0.f};
    const _Float16* ars = &xs16[lane & 15][(lane >> 4) << 3];
    const _Float16* bp = bf + (size_t)wave * 512 + (size_t)lane * 8;
    for (int t = 0; t < TSTEPS; t++) {
        f16x8 av = *(const f16x8*)(ars + t * 32);
        f16x8 bv = *(const f16x8*)(bp + (size_t)t * 4096);
        acc = __builtin_amdgcn_mfma_f32_16x16x32_f16(av, bv, acc, 0, 0, 0);
    }

    const float inv6 = 1.0f / 6.0f;
    const int cl = lane & 15;
    const int ccol = wave * 16 + cl;
    const int r0 = (lane >> 4) << 2;
    const float bs = bias[ccol];
    #pragma unroll
    for (int reg = 0; reg < 4; reg++) {
        int ml = r0 + reg;
        int m = m0 + ml;
        float v = acc[reg] * inv6 + bs;
        v = v > 0.f ? v : 0.f;
        if (ml < NPB && m < M) xout[(size_t)m * D + ccol] = v;
        xso[ml][ccol] = (_Float16)v;
    }

    // phase 3: fused next-layer attention logits (wave 0)
    if (awf) {
        __syncthreads();
        if (wave == 0) {
            f32x4 ac = {0.f, 0.f, 0.f, 0.f};
            #pragma unroll
            for (int t = 0; t < 4; t++) {
                f16x8 av = *(const f16x8*)&xso[cl][t * 32 + ((lane >> 4) << 3)];
                f16x8 bv = *(const f16x8*)(awf + (size_t)t * 512 + (size_t)lane * 8);
                ac = __builtin_amdgcn_mfma_f32_16x16x32_f16(av, bv, ac, 0, 0, 0);
            }
            if (cl < 12) {
                #pragma unroll
                for (int reg = 0; reg < 4; reg++) {
                    int ml = r0 + reg;
                    int m = m0 + ml;
                    if (ml < NPB && m < M) a_out[(size_t)m * 12 + cl] = ac[reg];
                }
            }
        }
    }
}

// ---------------- host ----------------

extern "C" void kernel_launch(void* const* d_in, const int* in_sizes, int n_in,
                              void* d_out, int out_size, void* d_ws, size_t ws_size,
                              hipStream_t stream) {
    const float* x_in = (const float*)d_in[0];
    const int* ei = (const int*)d_in[1];
    int N = in_sizes[0] / D;
    int E = in_sizes[1] / 2;
    const int* srcp = ei;
    const int* dstp = ei + E;

    size_t bf_halves_per_layer = (size_t)TSTEPS * 8 * 512;   // 98304

    float* ws = (float*)d_ws;
    float* bufA = ws;
    float* bufB = bufA + (size_t)N * D;
    float* abuf0 = bufB + (size_t)N * D;
    float* abuf1 = abuf0 + (size_t)N * 12;
    float* wa_all = abuf1 + (size_t)N * 12;          // 4*1536 floats
    _Float16* waf = (_Float16*)(wa_all + 4 * 1536);  // 4 layers x 2048 halves
    _Float16* w16f = waf + 4 * 2048;
    int* deg = (int*)(w16f + 4 * bf_halves_per_layer);
    int* col = deg + N;                               // N * BSTRIDE ints

    FoldArgs fa;
    for (int l = 0; l < 4; l++) {
        fa.W[l]  = (const float*)d_in[2 + 4 * l];
        fa.as[l] = (const float*)d_in[3 + 4 * l];
        fa.ad[l] = (const float*)d_in[4 + 4 * l];
    }

    // K1: zero deg + wa_all dots
    int n4 = (N + 3) / 4;
    int zBlocks = (n4 + 255) / 256;
    zero_wa_kernel<<<zBlocks + 24, 256, 0, stream>>>((int4*)deg, n4, zBlocks, fa, wa_all);

    // K2: scatter-hist | bf pack | waf pack | layer-0 a
    int scatBlocks = (E + 255) / 256;
    int a0Blocks = (N + 15) / 16;
    prep2_kernel<<<scatBlocks + 192 + 4 + a0Blocks, 256, 0, stream>>>(
        srcp, dstp, deg, col, E, scatBlocks, fa, wa_all, waf, w16f, x_in, abuf0, N);

    const float* xcur = x_in;
    float* acur = abuf0;
    float* anext = abuf1;
    for (int l = 0; l < 4; l++) {
        const float* b = (const float*)d_in[5 + 4 * l];
        float* xout = (l == 3) ? (float*)d_out : ((l & 1) ? bufB : bufA);
        const _Float16* awf = (l < 3) ? (waf + (size_t)(l + 1) * 2048) : (const _Float16*)nullptr;

        layer_kernel<<<(N + NPB - 1) / NPB, 512, 0, stream>>>(xcur, acur, deg, col,
                                                              w16f + (size_t)l * bf_halves_per_layer,
                                                              b, xout, awf, anext, N);
        xcur = xout;
        float* tmp = acur; acur = anext; anext = tmp;
    }
}